// Round 14
// baseline (934.327 us; speedup 1.0000x reference)
//
#include <hip/hip_runtime.h>
#include <hip/hip_bf16.h>

typedef __hip_bfloat16 bf16;

__device__ __forceinline__ float b2f(bf16 v) { return __bfloat162float(v); }
__device__ __forceinline__ bf16  f2b(float v) { return __float2bfloat16(v); }

__device__ __forceinline__ float ldany(int isbf, const void* p, int i)
{
    return isbf ? b2f(((const bf16*)p)[i]) : ((const float*)p)[i];
}

#define SELU_SCALE 1.0507009873554805f
#define SELU_ALPHA 1.6732632423543772f
#define INV_SQRT2  0.7071067811865475f
#define SELU_F(v) ((v) > 0.f ? SELU_SCALE * (v) : SELU_SCALE * SELU_ALPHA * expm1f(v))

#define NB 2048   // batch (fixed by reference)

// dtype flag + global staging
__device__ int   g_flag;                        // 1 = bf16 tensors, 0 = f32
__device__ float g_xin [(size_t)NB * 310];      // f32 copy of x
__device__ float g_qkv [(size_t)NB * 3348];     // qkv partial (f<160, + bias)
__device__ float g_qkvB[(size_t)NB * 3348];     // qkv partial (f>=160)
__device__ float g_x2t [(size_t)NB * 1860];     // attention output (pre-lin1)
__device__ float g_xx1 [(size_t)NB * 1860];     // conv-branch output
__device__ float g_xt  [(size_t)NB * 310];      // transformer output
__device__ float g_x11f[(size_t)NB * 620];      // f32 copy of x11 for k_fc
__device__ float g_L   [3844];                  // normalized Laplacian

// transposed (contraction-contiguous) f32 weights; row strides padded to 16B
__device__ float g_qkvT [(size_t)3348 * 312];   // [o][f] f<310 valid
__device__ float g_lin1T[(size_t)310 * 1860];   // [o][f]
__device__ float g_ffn1T[(size_t)186 * 312];    // [j][f] f<310 valid
__device__ float g_ffn2T[(size_t)310 * 188];    // [o][j] j<186 valid
__device__ float g_fc1T [(size_t)256 * 620];    // [o][f]
__device__ __align__(16) float g_gatW[4480];    // [h][f][o] f32 copy of gat_w
__device__ __align__(16) float g_outW[1280];    // [f][o]    f32 copy of out_w
// conv weights transposed to [(i*K+k)][o] with o padded to 64 (o>=62 -> 0)
#define CW3T_ONE (62 * 3 * 64)                  // 11904
#define CW5T_ONE (62 * 5 * 64)                  // 19840
#define CW3T_SZ  (4 * CW3T_ONE)                 // 47616
#define CW5T_SZ  (3 * CW5T_ONE)                 // 59520
__device__ __align__(16) float g_cwT[CW3T_SZ + CW5T_SZ];

// f32 staged small params
__device__ float g_cb3[248], g_cb5[186], g_bng[434], g_bnb[434];
__device__ float g_caw1[1860], g_caw2[1860];
__device__ float g_qb[744], g_kb[744], g_vb[1860];
__device__ float g_lin1b[310], g_ln1g[5], g_ln1bb[5], g_ln2g[5], g_ln2bb[5];
__device__ float g_ffnb1[186], g_ffnb2[310];
__device__ float g_gata[256], g_outa[20];
__device__ float g_fc1b[256], g_fc2w[8192], g_fc2b[32], g_fc3w[128], g_fc3b[4];

// ---- dtype probe ----
__global__ void k_probe(const void* x0)
{
    __shared__ int cnt;
    if (threadIdx.x == 0) cnt = 0;
    __syncthreads();
    const bf16* p = (const bf16*)x0;
    int bad = 0;
    for (int i = threadIdx.x; i < 4096; i += 256) {
        float v = b2f(p[i]);
        if (!(fabsf(v) < 1e6f)) bad++;
    }
    atomicAdd(&cnt, bad);
    __syncthreads();
    if (threadIdx.x == 0) g_flag = (cnt < 32) ? 1 : 0;
}

// ---- one-time big-array transposes / conversions (runtime dtype branch) ----
#define QKVT_SZ  (3348 * 312)
#define LIN1T_SZ (310 * 1860)
#define FFN1T_SZ (186 * 312)
#define FFN2T_SZ (310 * 188)
#define FC1T_SZ  (256 * 620)
#define GATW_SZ  4480
#define OUTW_SZ  1280
#define XIN_SZ   (NB * 310)
#define WPREP_TOTAL (QKVT_SZ + LIN1T_SZ + FFN1T_SZ + FFN2T_SZ + FC1T_SZ + GATW_SZ + OUTW_SZ + XIN_SZ + CW3T_SZ + CW5T_SZ)

__global__ __launch_bounds__(256) void k_wprep(
    const void* __restrict__ qw, const void* __restrict__ kw, const void* __restrict__ vw,
    const void* __restrict__ lin1_w, const void* __restrict__ ffn_w1, const void* __restrict__ ffn_w2,
    const void* __restrict__ fc1_w, const void* __restrict__ gat_w, const void* __restrict__ out_w,
    const void* __restrict__ x, const void* __restrict__ cw3, const void* __restrict__ cw5)
{
    const int isbf = g_flag;
    int idx = blockIdx.x * 256 + threadIdx.x;
    if (idx >= WPREP_TOTAL) return;
    if (idx < QKVT_SZ) {
        int o = idx / 312, f = idx - o * 312;
        float v = 0.f;
        if (f < 310) {
            if (o < 744)       { int h = o / 124, c = o - h * 124; v = ldany(isbf, qw, h * 38440 + f * 124 + c); }
            else if (o < 1488) { int r = o - 744;  int h = r / 124, c = r - h * 124; v = ldany(isbf, kw, h * 38440 + f * 124 + c); }
            else               { int r = o - 1488; int h = r / 310, c = r - h * 310; v = ldany(isbf, vw, h * 96100 + f * 310 + c); }
        }
        g_qkvT[idx] = v;
        return;
    }
    idx -= QKVT_SZ;
    if (idx < LIN1T_SZ) {
        int o = idx / 1860, f = idx - o * 1860;
        g_lin1T[idx] = ldany(isbf, lin1_w, f * 310 + o);
        return;
    }
    idx -= LIN1T_SZ;
    if (idx < FFN1T_SZ) {
        int j = idx / 312, f = idx - j * 312;
        g_ffn1T[idx] = (f < 310) ? ldany(isbf, ffn_w1, f * 186 + j) : 0.f;
        return;
    }
    idx -= FFN1T_SZ;
    if (idx < FFN2T_SZ) {
        int o = idx / 188, j = idx - o * 188;
        g_ffn2T[idx] = (j < 186) ? ldany(isbf, ffn_w2, j * 310 + o) : 0.f;
        return;
    }
    idx -= FFN2T_SZ;
    if (idx < FC1T_SZ) {
        int o = idx / 620, f = idx - o * 620;
        g_fc1T[idx] = ldany(isbf, fc1_w, f * 256 + o);
        return;
    }
    idx -= FC1T_SZ;
    if (idx < GATW_SZ) { g_gatW[idx] = ldany(isbf, gat_w, idx); return; }
    idx -= GATW_SZ;
    if (idx < OUTW_SZ) { g_outW[idx] = ldany(isbf, out_w, idx); return; }
    idx -= OUTW_SZ;
    if (idx < XIN_SZ) { g_xin[idx] = ldany(isbf, x, idx); return; }
    idx -= XIN_SZ;
    if (idx < CW3T_SZ) {
        int c = idx / CW3T_ONE, r = idx - c * CW3T_ONE;
        int ik = r >> 6, o = r & 63;
        g_cwT[idx] = (o < 62) ? ldany(isbf, cw3, c * 11532 + o * 186 + ik) : 0.f;
        return;
    }
    idx -= CW3T_SZ;
    {
        int c = idx / CW5T_ONE, r = idx - c * CW5T_ONE;
        int ik = r >> 6, o = r & 63;
        g_cwT[CW3T_SZ + idx] = (o < 62) ? ldany(isbf, cw5, c * 19220 + o * 310 + ik) : 0.f;
    }
}

// ---- Laplacian + all small-param conversions (runtime dtype branch) ----
__global__ __launch_bounds__(256) void k_prep(
    const void* __restrict__ A,
    const void* __restrict__ cb3, const void* __restrict__ cb5,
    const void* __restrict__ bn_g, const void* __restrict__ bn_b,
    const void* __restrict__ ca_w1, const void* __restrict__ ca_w2,
    const void* __restrict__ qb, const void* __restrict__ kb, const void* __restrict__ vb,
    const void* __restrict__ lin1_b,
    const void* __restrict__ ln1_g, const void* __restrict__ ln1_b,
    const void* __restrict__ ln2_g, const void* __restrict__ ln2_b,
    const void* __restrict__ ffn_b1, const void* __restrict__ ffn_b2,
    const void* __restrict__ gat_a, const void* __restrict__ out_a,
    const void* __restrict__ fc1_b, const void* __restrict__ fc2_w, const void* __restrict__ fc2_b,
    const void* __restrict__ fc3_w, const void* __restrict__ fc3_b)
{
    const int isbf = g_flag;
    __shared__ float sdinv[62];
    const int tid = threadIdx.x;
    if (blockIdx.x == 0) {
        if (tid < 62) {
            float s = 0.f;
            for (int m = 0; m < 62; ++m) s += fmaxf(ldany(isbf, A, tid * 62 + m), 0.f);
            sdinv[tid] = rsqrtf(s + 1e-10f);
        }
        __syncthreads();
        for (int idx = tid; idx < 3844; idx += 256) {
            int n = idx / 62, m = idx - n * 62;
            g_L[idx] = sdinv[n] * fmaxf(ldany(isbf, A, idx), 0.f) * sdinv[m];
        }
        return;
    }
    int idx = (blockIdx.x - 1) * 256 + tid;
#define CP(dst, src, n) { if (idx < (n)) { dst[idx] = ldany(isbf, src, idx); return; } idx -= (n); }
    CP(g_cb3, cb3, 248) CP(g_cb5, cb5, 186)
    CP(g_bng, bn_g, 434) CP(g_bnb, bn_b, 434)
    CP(g_caw1, ca_w1, 1860) CP(g_caw2, ca_w2, 1860)
    CP(g_qb, qb, 744) CP(g_kb, kb, 744) CP(g_vb, vb, 1860)
    CP(g_lin1b, lin1_b, 310)
    CP(g_ln1g, ln1_g, 5) CP(g_ln1bb, ln1_b, 5) CP(g_ln2g, ln2_g, 5) CP(g_ln2bb, ln2_b, 5)
    CP(g_ffnb1, ffn_b1, 186) CP(g_ffnb2, ffn_b2, 310)
    CP(g_gata, gat_a, 256) CP(g_outa, out_a, 20)
    CP(g_fc1b, fc1_b, 256) CP(g_fc2w, fc2_w, 8192) CP(g_fc2b, fc2_b, 32)
    CP(g_fc3w, fc3_w, 128) CP(g_fc3b, fc3_b, 4)
#undef CP
}

// ================= conv branch, G=4 samples/block (R10-proven) =================
template<int K>
__device__ void conv_g(int tid, const float* sIn, int Lin, int Lout,
                       const float* __restrict__ WT,
                       const float* __restrict__ cb, const float* __restrict__ bng,
                       const float* __restrict__ bnb,
                       float* sOut, int ostride, int ooff)
{
    const float bninv = rsqrtf(1.0f + 1e-5f);
    if (tid < 16 * Lout) {
        int oq = tid / Lout, l = tid - oq * Lout;
        const float* wp = WT + oq * 4;
        float4 c0 = {0,0,0,0}, c1 = {0,0,0,0}, c2 = {0,0,0,0}, c3 = {0,0,0,0};
        #pragma unroll 2
        for (int i = 0; i < 62; ++i) {
            #pragma unroll
            for (int k = 0; k < K; ++k) {
                const float4 w  = *(const float4*)(wp + (i * K + k) * 64);
                const float4 xv = *(const float4*)(sIn + (i * Lin + l + k) * 4);
                c0.x += w.x * xv.x; c0.y += w.x * xv.y; c0.z += w.x * xv.z; c0.w += w.x * xv.w;
                c1.x += w.y * xv.x; c1.y += w.y * xv.y; c1.z += w.y * xv.z; c1.w += w.y * xv.w;
                c2.x += w.z * xv.x; c2.y += w.z * xv.y; c2.z += w.z * xv.z; c2.w += w.z * xv.w;
                c3.x += w.w * xv.x; c3.y += w.w * xv.y; c3.z += w.w * xv.z; c3.w += w.w * xv.w;
            }
        }
        float4 cc[4] = {c0, c1, c2, c3};
        #pragma unroll
        for (int oo = 0; oo < 4; ++oo) {
            int o = oq * 4 + oo;
            if (o < 62) {
                float bias = cb[o], gg = bng[o] * bninv, bb = bnb[o];
                float v0 = (cc[oo].x + bias) * gg + bb;
                float v1 = (cc[oo].y + bias) * gg + bb;
                float v2 = (cc[oo].z + bias) * gg + bb;
                float v3 = (cc[oo].w + bias) * gg + bb;
                float4 r;
                r.x = SELU_F(v0); r.y = SELU_F(v1); r.z = SELU_F(v2); r.w = SELU_F(v3);
                *(float4*)(sOut + (o * ostride + ooff + l) * 4) = r;
            }
        }
    }
    __syncthreads();
}

__device__ void chan_att_g(int tid, float* sIn, int Ls,
                           const float* __restrict__ w1, const float* __restrict__ w2,
                           float* pool, float* hid)
{
    __syncthreads();
    for (int idx = tid; idx < 496; idx += 256) {
        int which = idx >= 248; int r = idx - which * 248;
        int n = r >> 2, g = r & 3;
        float a = 0.f, m = -3.4e38f;
        for (int l = 0; l < Ls; ++l) { float v = sIn[(n * Ls + l) * 4 + g]; a += v; m = fmaxf(m, v); }
        pool[(which * 62 + n) * 4 + g] = which ? m : a / (float)Ls;
    }
    __syncthreads();
    if (tid < 120) {
        int g = tid & 3; int t = tid >> 2;
        int which = t / 15, j = t - which * 15;
        float acc = 0.f;
        for (int n = 0; n < 62; ++n) acc += pool[(which * 62 + n) * 4 + g] * w1[j * 62 + n];
        hid[(which * 16 + j) * 4 + g] = fmaxf(acc, 0.f);
    }
    __syncthreads();
    if (tid < 248) {
        int g = tid & 3, n = tid >> 2;
        float acc = 0.f;
        for (int j = 0; j < 15; ++j) acc += (hid[j * 4 + g] + hid[(16 + j) * 4 + g]) * w2[n * 15 + j];
        float s = 1.f / (1.f + expf(-acc));
        for (int l = 0; l < Ls; ++l) sIn[(n * Ls + l) * 4 + g] *= s;
    }
    __syncthreads();
}

__global__ __launch_bounds__(256) void k_conv()
{
    __shared__ __align__(16) float sx2[496 * 4];
    __shared__ __align__(16) float sbuf[868 * 4];
    __shared__ __align__(16) float sxx1[1860 * 4];
    const int tid = threadIdx.x;
    const int grp = blockIdx.x;
    const float* cw3T = g_cwT;
    const float* cw5T = g_cwT + CW3T_SZ;
    float* spool = sbuf;          // sbuf dead during both chan_att calls
    float* shid  = sbuf + 496;

    for (int idx = tid; idx < 310 * 4; idx += 256) {
        int p = idx >> 2, g = idx & 3; int n = p / 5, c = p - n * 5;
        sx2[(n * 8 + 3 + c) * 4 + g] = g_xin[(size_t)(grp * 4 + g) * 310 + p];
    }
    __syncthreads();

    conv_g<3>(tid, sx2 + 12, 8, 3, cw3T, g_cb3, g_bng, g_bnb, sx2, 8, 0);
    chan_att_g(tid, sx2, 8, g_caw1, g_caw2, spool, shid);

    conv_g<3>(tid, sx2, 8, 6, cw3T + CW3T_ONE, g_cb3 + 62, g_bng + 62, g_bnb + 62, sbuf, 14, 8);
    for (int idx = tid; idx < 496 * 4; idx += 256) {
        int p = idx >> 2, g = idx & 3; int n = p >> 3, c = p & 7;
        sbuf[(n * 14 + c) * 4 + g] = sx2[idx];
    }
    __syncthreads();
    conv_g<3>(tid, sbuf, 14, 12, cw3T + 2 * CW3T_ONE, g_cb3 + 124, g_bng + 124, g_bnb + 124, sxx1, 30, 0);

    conv_g<5>(tid, sx2, 8, 4, cw5T, g_cb5, g_bng + 186, g_bnb + 186, sbuf, 12, 0);
    for (int idx = tid; idx < 496 * 4; idx += 256) {
        int p = idx >> 2, g = idx & 3; int n = p >> 3, c = p & 7;
        sbuf[(n * 12 + 4 + c) * 4 + g] = sx2[idx];
    }
    __syncthreads();
    conv_g<5>(tid, sbuf, 12, 8, cw5T + CW5T_ONE, g_cb5 + 62, g_bng + 248, g_bnb + 248, sxx1, 30, 12);

    conv_g<3>(tid, sx2, 8, 6, cw3T + 3 * CW3T_ONE, g_cb3 + 186, g_bng + 310, g_bnb + 310, sbuf, 14, 0);
    for (int idx = tid; idx < 496 * 4; idx += 256) {
        int p = idx >> 2, g = idx & 3; int n = p >> 3, c = p & 7;
        sbuf[(n * 14 + 6 + c) * 4 + g] = sx2[idx];
    }
    __syncthreads();
    conv_g<5>(tid, sbuf, 14, 10, cw5T + 2 * CW5T_ONE, g_cb5 + 124, g_bng + 372, g_bnb + 372, sxx1, 30, 20);

    chan_att_g(tid, sxx1, 30, g_caw1 + 930, g_caw2 + 930, spool, shid);

    for (int idx = tid; idx < 1860 * 4; idx += 256) {
        int p = idx >> 2, g = idx & 3;
        g_xx1[(size_t)(grp * 4 + g) * 1860 + p] = sxx1[idx];
    }
}

// ================= transformer =================
// QKV GEMM R14: 16 samples/block, OB=2, f-SPLIT (310=160+150, node-aligned).
// Grid (B/16)*14 = 1792 blocks (7/CU) with OB=2 amortization intact.
// half 0 -> g_qkv (with bias); half 1 -> g_qkvB; k_attn adds them.
__global__ __launch_bounds__(256) void k_qkv()
{
    __shared__ __align__(16) float sxf[160 * 16];
    const int tid = threadIdx.x;
    const int bid = blockIdx.x;
    const int grp = bid / 14;
    const int r = bid - grp * 14;
    const int tile = r >> 1;
    const int half = r & 1;
    const int fbase = half ? 160 : 0;
    const int flen  = half ? 150 : 160;

    for (int idx = tid; idx < flen * 16; idx += 256) {
        int f = idx >> 4, g = idx & 15;
        sxf[idx] = g_xin[(size_t)(grp * 16 + g) * 310 + fbase + f];
    }
    __syncthreads();
    // LN1 in place: whole nodes per half (160/5=32, 150/5=30)
    const int nNodes = flen / 5;
    for (int it = tid; it < nNodes * 16; it += 256) {
        int i = it >> 4, g = it & 15;
        float xv[5], m = 0.f, s = 0.f;
        #pragma unroll
        for (int c = 0; c < 5; ++c) { xv[c] = sxf[(i * 5 + c) * 16 + g]; m += xv[c]; s += xv[c] * xv[c]; }
        m *= 0.2f;
        float inv = rsqrtf(fmaxf(s * 0.2f - m * m, 0.f) + 1e-5f);
        #pragma unroll
        for (int c = 0; c < 5; ++c)
            sxf[(i * 5 + c) * 16 + g] = (xv[c] - m) * inv * g_ln1g[c] + g_ln1bb[c];
    }
    __syncthreads();

    int o0 = tile * 512 + tid;
    if (o0 >= 3348) return;
    int o1 = o0 + 256;
    const int valid1 = (o1 < 3348);
    int o1c = valid1 ? o1 : 3347;   // clamp: reads valid memory, result discarded

    float bias0 = 0.f, bias1 = 0.f;
    if (!half) {
        bias0 = (o0 < 744) ? g_qb[o0] : (o0 < 1488) ? g_kb[o0 - 744] : g_vb[o0 - 1488];
        bias1 = (o1c < 744) ? g_qb[o1c] : (o1c < 1488) ? g_kb[o1c - 744] : g_vb[o1c - 1488];
    }
    const float* W0 = g_qkvT + (size_t)o0 * 312 + fbase;
    const float* W1 = g_qkvT + (size_t)o1c * 312 + fbase;

    float accA[16], accB[16];
    #pragma unroll
    for (int g = 0; g < 16; ++g) { accA[g] = bias0; accB[g] = bias1; }

#define QS2(wka, wkb, ff) { \
    const float4* xp = (const float4*)(sxf + (ff) * 16); \
    const float4 x0 = xp[0], x1 = xp[1], x2 = xp[2], x3 = xp[3]; \
    float xs[16]; \
    *(float4*)(xs) = x0; *(float4*)(xs + 4) = x1; *(float4*)(xs + 8) = x2; *(float4*)(xs + 12) = x3; \
    _Pragma("unroll") \
    for (int g = 0; g < 16; ++g) { accA[g] += (wka) * xs[g]; accB[g] += (wkb) * xs[g]; } }

    const int f4 = flen & ~3;   // 160 / 148
    for (int f = 0; f < f4; f += 4) {
        const float4 wa = *(const float4*)(W0 + f);
        const float4 wb = *(const float4*)(W1 + f);
        QS2(wa.x, wb.x, f) QS2(wa.y, wb.y, f + 1) QS2(wa.z, wb.z, f + 2) QS2(wa.w, wb.w, f + 3)
    }
    for (int f = f4; f < flen; ++f) QS2(W0[f], W1[f], f)
#undef QS2

    float* dst = half ? g_qkvB : g_qkv;
    #pragma unroll
    for (int g = 0; g < 16; ++g) {
        size_t base = (size_t)(grp * 16 + g) * 3348;
        dst[base + o0] = accA[g];
        if (valid1) dst[base + o1] = accB[g];
    }
}

// per-sample attention -> g_x2t (parallel row-softmax; rcp pass + v-fold; PV 2-read)
__global__ __launch_bounds__(256) void k_attn()
{
    __shared__ float sqkv[3348];
    __shared__ float satt[3844];
    __shared__ float sred[496];
    const int tid = threadIdx.x;
    const int b = blockIdx.x;

    for (int i = tid; i < 3348; i += 256)
        sqkv[i] = g_qkv[(size_t)b * 3348 + i] + g_qkvB[(size_t)b * 3348 + i];
    __syncthreads();

    for (int h = 0; h < 6; ++h) {
        const float* q = sqkv + h * 124;
        const float* k = sqkv + 744 + h * 124;
        float* v = sqkv + 1488 + h * 310;
        for (int idx = tid; idx < 3844; idx += 256) {
            int i = idx / 62, j = idx - i * 62;
            satt[idx] = (q[i * 2] * k[j * 2] + q[i * 2 + 1] * k[j * 2 + 1]) * INV_SQRT2;
        }
        __syncthreads();
        if (tid < 248) {
            int qq = tid / 62, i = tid - qq * 62;
            int j0 = qq * 16, j1 = j0 + 16 > 62 ? 62 : j0 + 16;
            const float* row = satt + i * 62;
            float mx = -3.4e38f;
            for (int j = j0; j < j1; ++j) mx = fmaxf(mx, row[j]);
            sred[qq * 62 + i] = mx;
        }
        __syncthreads();
        if (tid < 248) {
            int qq = tid / 62, i = tid - qq * 62;
            int j0 = qq * 16, j1 = j0 + 16 > 62 ? 62 : j0 + 16;
            float rmx = fmaxf(fmaxf(sred[i], sred[62 + i]), fmaxf(sred[124 + i], sred[186 + i]));
            float* row = satt + i * 62;
            float s = 0.f;
            for (int j = j0; j < j1; ++j) { float e = expf(row[j] - rmx); row[j] = e; s += e; }
            sred[248 + qq * 62 + i] = s;
        }
        __syncthreads();
        if (tid < 62)
            sred[tid] = 1.f / (sred[248 + tid] + sred[310 + tid] + sred[372 + tid] + sred[434 + tid]);
        __syncthreads();
        for (int t = tid; t < 310; t += 256) v[t] *= sred[t / 5];
        __syncthreads();
        for (int idx = tid; idx < 310; idx += 256) {
            int i = idx / 5, c = idx - i * 5;
            float acc = 0.f;
            for (int j = 0; j < 62; ++j) acc += satt[j * 62 + i] * v[j * 5 + c];
            g_x2t[(size_t)b * 1860 + i * 30 + h * 5 + c] = acc;
        }
        __syncthreads();
    }
}

// lin1 + residual + LN2 + FFN + residual: 4 samples/block (R13 body)
__global__ __launch_bounds__(256) void k_lin1ffn()
{
    __shared__ __align__(16) float sx2t[1860 * 4];   // later reused: sxf[0:1240) | shg[1240:1984)
    __shared__ __align__(16) float sx21[310 * 4];
    const int tid = threadIdx.x;
    const int grp = blockIdx.x;

    for (int idx = tid; idx < 1860 * 4; idx += 256) {
        int f = idx >> 2, g = idx & 3;
        sx2t[idx] = g_x2t[(size_t)(grp * 4 + g) * 1860 + f];
    }
    __syncthreads();

#define XSTEP(wk, ff, Xb) { const float4 xv = *(const float4*)((Xb) + (ff) * 4); \
                            a0 += (wk) * xv.x; a1 += (wk) * xv.y; a2 += (wk) * xv.z; a3 += (wk) * xv.w; }
    for (int o = tid; o < 310; o += 256) {
        const float* W = g_lin1T + (size_t)o * 1860;
        float a0 = 0.f, a1 = 0.f, a2 = 0.f, a3 = 0.f;
        for (int f = 0; f < 1860; f += 4) {
            const float4 w = *(const float4*)(W + f);
            XSTEP(w.x, f, sx2t) XSTEP(w.y, f + 1, sx2t) XSTEP(w.z, f + 2, sx2t) XSTEP(w.w, f + 3, sx2t)
        }
        float bias = g_lin1b[o];
        sx21[o * 4 + 0] = a0 + bias + g_xin[(size_t)(grp * 4 + 0) * 310 + o];
        sx21[o * 4 + 1] = a1 + bias + g_xin[(size_t)(grp * 4 + 1) * 310 + o];
        sx21[o * 4 + 2] = a2 + bias + g_xin[(size_t)(grp * 4 + 2) * 310 + o];
        sx21[o * 4 + 3] = a3 + bias + g_xin[(size_t)(grp * 4 + 3) * 310 + o];
    }
    __syncthreads();

    float* sxf = sx2t;           // [1240] (sx2t dead after lin1 pass)
    float* shg = sx2t + 1240;    // [744]

    if (tid < 248) {
        int i = tid >> 2, g = tid & 3;
        float m = 0.f, s = 0.f;
        for (int c = 0; c < 5; ++c) { float v = sx21[(i * 5 + c) * 4 + g]; m += v; s += v * v; }
        m *= 0.2f;
        float inv = rsqrtf(fmaxf(s * 0.2f - m * m, 0.f) + 1e-5f);
        for (int c = 0; c < 5; ++c)
            sxf[(i * 5 + c) * 4 + g] = (sx21[(i * 5 + c) * 4 + g] - m) * inv * g_ln2g[c] + g_ln2bb[c];
    }
    __syncthreads();

    if (tid < 186) {
        const float* W = g_ffn1T + (size_t)tid * 312;
        float bias = g_ffnb1[tid];
        float a0 = bias, a1 = bias, a2 = bias, a3 = bias;
        for (int f = 0; f < 308; f += 4) {
            const float4 w = *(const float4*)(W + f);
            XSTEP(w.x, f, sxf) XSTEP(w.y, f + 1, sxf) XSTEP(w.z, f + 2, sxf) XSTEP(w.w, f + 3, sxf)
        }
        XSTEP(W[308], 308, sxf) XSTEP(W[309], 309, sxf)
        shg[tid * 4 + 0] = 0.5f * a0 * (1.f + erff(a0 * INV_SQRT2));
        shg[tid * 4 + 1] = 0.5f * a1 * (1.f + erff(a1 * INV_SQRT2));
        shg[tid * 4 + 2] = 0.5f * a2 * (1.f + erff(a2 * INV_SQRT2));
        shg[tid * 4 + 3] = 0.5f * a3 * (1.f + erff(a3 * INV_SQRT2));
    }
    __syncthreads();

    for (int o = tid; o < 310; o += 256) {
        const float* W = g_ffn2T + (size_t)o * 188;
        float bias = g_ffnb2[o];
        float a0 = bias, a1 = bias, a2 = bias, a3 = bias;
        for (int j = 0; j < 184; j += 4) {
            const float4 w = *(const float4*)(W + j);
            XSTEP(w.x, j, shg) XSTEP(w.y, j + 1, shg) XSTEP(w.z, j + 2, shg) XSTEP(w.w, j + 3, shg)
        }
        XSTEP(W[184], 184, shg) XSTEP(W[185], 185, shg)
        g_xt[(size_t)(grp * 4 + 0) * 310 + o] = a0 + sx21[o * 4 + 0];
        g_xt[(size_t)(grp * 4 + 1) * 310 + o] = a1 + sx21[o * 4 + 1];
        g_xt[(size_t)(grp * 4 + 2) * 310 + o] = a2 + sx21[o * 4 + 2];
        g_xt[(size_t)(grp * 4 + 3) * 310 + o] = a3 + sx21[o * 4 + 3];
    }
#undef XSTEP
}

// ================= GAT (R9-proven: fold passes + register layer-2 accum) =================
__global__ __launch_bounds__(256) void k_gat(void* __restrict__ out, int B)
{
    __shared__ __align__(16) float satt[3844];
    __shared__ __align__(16) float sh[1984];
    __shared__ __align__(16) float sbufA[2170];   // layer1: f32 sxx; layer2: soutg
    __shared__ float ssrc[124];
    __shared__ float sred[496];
    __shared__ float sacc2[620];
    const int tid = threadIdx.x;
    const int b = blockIdx.x;
    const int isbf = g_flag;
    float* sxx = sbufA;

    for (int idx = tid; idx < 2170; idx += 256) {
        int n = idx / 35, f = idx - n * 35;
        sxx[idx] = (f < 30) ? g_xx1[(size_t)b * 1860 + n * 30 + f]
                            : g_xt[(size_t)b * 310 + n * 5 + (f - 30)];
    }

    float racc0[10], racc1[10];
    #pragma unroll
    for (int o = 0; o < 10; ++o) { racc0[o] = 0.f; racc1[o] = 0.f; }

    for (int h = 0; h < 4; ++h) {
        for (int idx = tid; idx < 1120; idx += 256) satt[idx] = g_gatW[h * 1120 + idx];
        __syncthreads();
        float* sp1 = satt + 1200;
        float* sp2 = satt + 1800;
        for (int item = tid; item < 496; item += 256) {
            int n = item >> 3, oqi = item & 7, oq = oqi * 4;
            const float* xr = sxx + n * 35;
            float a0 = 0.f, a1 = 0.f, a2 = 0.f, a3 = 0.f;
            for (int f = 0; f < 35; ++f) {
                float xv = xr[f];
                const float4 w = *(const float4*)(satt + f * 32 + oq);
                a0 += xv * w.x; a1 += xv * w.y; a2 += xv * w.z; a3 += xv * w.w;
            }
            float4 r; r.x = a0; r.y = a1; r.z = a2; r.w = a3;
            *(float4*)(sh + n * 32 + oq) = r;
            float l0 = a0 > 0.f ? a0 : 0.2f * a0;
            float l1 = a1 > 0.f ? a1 : 0.2f * a1;
            float l2 = a2 > 0.f ? a2 : 0.2f * a2;
            float l3 = a3 > 0.f ? a3 : 0.2f * a3;
            const float* ga = g_gata + h * 64 + oq;
            sp1[n * 9 + oqi] = l0 * ga[0] + l1 * ga[1] + l2 * ga[2] + l3 * ga[3];
            sp2[n * 9 + oqi] = l0 * ga[32] + l1 * ga[33] + l2 * ga[34] + l3 * ga[35];
        }
        __syncthreads();
        if (tid < 124) {
            int which = tid >= 62; int n = tid - which * 62;
            const float* pp = which ? sp2 : sp1;
            float s = 0.f;
            for (int q = 0; q < 8; ++q) s += pp[n * 9 + q];
            ssrc[tid] = s;
        }
        __syncthreads();
        if (tid < 248) {
            int q = tid / 62, m = tid - q * 62;
            int n0 = q * 16, n1 = n0 + 16 > 62 ? 62 : n0 + 16;
            float s2m = ssrc[62 + m];
            float mx = -3.4e38f;
            for (int n = n0; n < n1; ++n) {
                float dj = 0.8f * g_L[n * 62 + m] + 0.2f * (ssrc[n] + s2m);
                dj = dj > 0.f ? dj : -1e12f;
                satt[n * 62 + m] = dj;
                mx = fmaxf(mx, dj);
            }
            sred[q * 62 + m] = mx;
        }
        __syncthreads();
        if (tid < 248) {
            int q = tid / 62, m = tid - q * 62;
            int n0 = q * 16, n1 = n0 + 16 > 62 ? 62 : n0 + 16;
            float cmx = fmaxf(fmaxf(sred[m], sred[62 + m]), fmaxf(sred[124 + m], sred[186 + m]));
            float s = 0.f;
            for (int n = n0; n < n1; ++n) {
                float e = expf(satt[n * 62 + m] - cmx);
                satt[n * 62 + m] = e;
                s += e;
            }
            sred[248 + q * 62 + m] = s;
        }
        __syncthreads();
        if (tid < 62)
            ssrc[tid] = 1.f / (sred[248 + tid] + sred[310 + tid] + sred[372 + tid] + sred[434 + tid]);
        __syncthreads();
        for (int item = tid; item < 1984; item += 256) sh[item] *= ssrc[item >> 5];
        __syncthreads();
        if (tid < 248) {
            int ip = tid >> 3, oqi = tid & 7, oq = oqi * 4;
            int i0 = ip * 2;
            const float* ar0 = satt + i0 * 62;
            const float* ar1 = ar0 + 62;
            float a00 = 0.f, a01 = 0.f, a02 = 0.f, a03 = 0.f;
            float a10 = 0.f, a11 = 0.f, a12 = 0.f, a13 = 0.f;
            for (int j = 0; j < 62; ++j) {
                const float4 hv = *(const float4*)(sh + j * 32 + oq);
                float v0 = ar0[j], v1 = ar1[j];
                a00 += v0 * hv.x; a01 += v0 * hv.y; a02 += v0 * hv.z; a03 += v0 * hv.w;
                a10 += v1 * hv.x; a11 += v1 * hv.y; a12 += v1 * hv.z; a13 += v1 * hv.w;
            }
            a00 = fmaxf(a00, 0.f); a01 = fmaxf(a01, 0.f); a02 = fmaxf(a02, 0.f); a03 = fmaxf(a03, 0.f);
            a10 = fmaxf(a10, 0.f); a11 = fmaxf(a11, 0.f); a12 = fmaxf(a12, 0.f); a13 = fmaxf(a13, 0.f);
            const float* W2 = g_outW + (h * 32 + oq) * 10;
            #pragma unroll
            for (int o = 0; o < 10; ++o) {
                float w0 = W2[o], w1 = W2[10 + o], w2c = W2[20 + o], w3 = W2[30 + o];
                racc0[o] += a00 * w0 + a01 * w1 + a02 * w2c + a03 * w3;
                racc1[o] += a10 * w0 + a11 * w1 + a12 * w2c + a13 * w3;
            }
        }
        __syncthreads();
    }

    if (tid < 248) {
        float* dst = satt + tid * 20;
        #pragma unroll
        for (int o = 0; o < 10; ++o) { dst[o] = racc0[o]; dst[10 + o] = racc1[o]; }
    }
    __syncthreads();
    for (int idx = tid; idx < 620; idx += 256) {
        int i = idx / 10, o = idx - i * 10;
        int ip = i >> 1, half = i & 1;
        const float* src = satt + (ip * 8) * 20 + half * 10 + o;
        float s = 0.f;
        #pragma unroll
        for (int q = 0; q < 8; ++q) s += src[q * 20];
        sacc2[idx] = s;
    }
    __syncthreads();

    float* sh2   = sacc2;
    float* soutg = sbufA;

    if (tid < 124) {
        int which = tid >= 62; int n = tid - which * 62;
        float acc = 0.f;
        for (int o = 0; o < 10; ++o) {
            float v = sh2[n * 10 + o]; v = v > 0.f ? v : 0.2f * v;
            acc += v * g_outa[which * 10 + o];
        }
        ssrc[tid] = acc;
    }
    __syncthreads();
    if (tid < 248) {
        int q = tid / 62, m = tid - q * 62;
        int n0 = q * 16, n1 = n0 + 16 > 62 ? 62 : n0 + 16;
        float s2m = ssrc[62 + m];
        float mx = -3.4e38f;
        for (int n = n0; n < n1; ++n) {
            float dj = 0.8f * g_L[n * 62 + m] + 0.2f * (ssrc[n] + s2m);
            dj = dj > 0.f ? dj : -1e12f;
            satt[n * 62 + m] = dj;
            mx = fmaxf(mx, dj);
        }
        sred[q * 62 + m] = mx;
    }
    __syncthreads();
    if (tid < 248) {
        int q = tid / 62, m = tid - q * 62;
        int n0 = q * 16, n1 = n0 + 16 > 62 ? 62 : n0 + 16;
        float cmx = fmaxf(fmaxf(sred[m], sred[62 + m]), fmaxf(sred[124 + m], sred[186 + m]));
        float s = 0.f;
        for (int n = n0; n < n1; ++n) {
            float e = expf(satt[n * 62 + m] - cmx);
            satt[n * 62 + m] = e;
            s += e;
        }
        sred[248 + q * 62 + m] = s;
    }
    __syncthreads();
    if (tid < 62)
        ssrc[tid] = 1.f / (sred[248 + tid] + sred[310 + tid] + sred[372 + tid] + sred[434 + tid]);
    __syncthreads();
    for (int item = tid; item < 620; item += 256) sh2[item] *= ssrc[item / 10];
    __syncthreads();
    for (int idx = tid; idx < 620; idx += 256) {
        int i = idx / 10, o = idx - i * 10;
        const float* ar = satt + i * 62;
        float acc = 0.f;
        for (int j = 0; j < 62; ++j) acc += ar[j] * sh2[j * 10 + o];
        soutg[idx] = fmaxf(acc, 0.f);
    }
    __syncthreads();

    if (tid < 62) {
        const float* r = soutg + tid * 10;
        float e[10]; float mx = -3.4e38f;
        for (int o = 0; o < 10; ++o) { float v = r[o]; v = v > 0.f ? v : expm1f(v); e[o] = v; mx = fmaxf(mx, v); }
        float sum = 0.f;
        for (int o = 0; o < 10; ++o) sum += expf(e[o] - mx);
        float ls = logf(sum) + mx;
        for (int o = 0; o < 10; ++o) {
            float v = e[o] - ls;
            size_t off = (size_t)b * 620 + tid * 10 + o;
            if (isbf) ((bf16*)out)[off] = f2b(v); else ((float*)out)[off] = v;
            g_x11f[off] = v;
        }
    }
}

// fc1->fc2->fc3 tail, 8 samples/block (R6-proven)
__global__ __launch_bounds__(256) void k_fc(void* __restrict__ out, int B)
{
    __shared__ __align__(16) float sxf[620 * 8];
    __shared__ __align__(16) float st1[256 * 8];
    __shared__ __align__(16) float st2[32 * 8];
    const int tid = threadIdx.x;
    const int grp = blockIdx.x;
    const int isbf = g_flag;

    for (int idx = tid; idx < 620 * 8; idx += 256) {
        int f = idx >> 3, g = idx & 7;
        sxf[idx] = g_x11f[(size_t)(grp * 8 + g) * 620 + f];
    }
    __syncthreads();

    {
        const float* W = g_fc1T + (size_t)tid * 620;
        float bias = g_fc1b[tid];
        float a0 = bias, a1 = bias, a2 = bias, a3 = bias, a4 = bias, a5 = bias, a6 = bias, a7 = bias;
#define FSTEP(wk, ff) { const float4 p = *(const float4*)(sxf + (ff) * 8); \
                        const float4 qq = *(const float4*)(sxf + (ff) * 8 + 4); \
                        a0 += (wk) * p.x; a1 += (wk) * p.y; a2 += (wk) * p.z; a3 += (wk) * p.w; \
                        a4 += (wk) * qq.x; a5 += (wk) * qq.y; a6 += (wk) * qq.z; a7 += (wk) * qq.w; }
        for (int f = 0; f < 620; f += 4) {
            const float4 w = *(const float4*)(W + f);
            FSTEP(w.x, f) FSTEP(w.y, f + 1) FSTEP(w.z, f + 2) FSTEP(w.w, f + 3)
        }
#undef FSTEP
        float4 r0; r0.x = a0; r0.y = a1; r0.z = a2; r0.w = a3;
        float4 r1; r1.x = a4; r1.y = a5; r1.z = a6; r1.w = a7;
        *(float4*)(st1 + tid * 8)     = r0;
        *(float4*)(st1 + tid * 8 + 4) = r1;
    }
    __syncthreads();
    {
        int g = tid >> 5, o = tid & 31;
        float acc = g_fc2b[o];
        for (int f = 0; f < 256; ++f) acc += st1[f * 8 + g] * g_fc2w[f * 32 + o];
        st2[o * 8 + g] = acc;
    }
    __syncthreads();
    if (tid < 32) {
        int g = tid >> 2, o = tid & 3;
        float acc = g_fc3b[o];
        for (int f = 0; f < 32; ++f) acc += st2[f * 8 + g] * g_fc3w[f * 4 + o];
        size_t off = (size_t)B * 620 + (size_t)(grp * 8 + g) * 4 + o;
        if (isbf) ((bf16*)out)[off] = f2b(acc); else ((float*)out)[off] = acc;
    }
}

extern "C" void kernel_launch(void* const* d_in, const int* in_sizes, int n_in,
                              void* d_out, int out_size, void* d_ws, size_t ws_size,
                              hipStream_t stream)
{
    const int B = in_sizes[0] / 310;   // 2048
    const int wprep_blocks = (WPREP_TOTAL + 255) / 256;

    k_probe<<<1, 256, 0, stream>>>(d_in[0]);

    k_wprep<<<wprep_blocks, 256, 0, stream>>>(
        d_in[10], d_in[12], d_in[14], d_in[16], d_in[22], d_in[24], d_in[30],
        d_in[26], d_in[28], d_in[0], d_in[2], d_in[4]);
    k_prep<<<72, 256, 0, stream>>>(
        d_in[1], d_in[3], d_in[5], d_in[6], d_in[7], d_in[8], d_in[9],
        d_in[11], d_in[13], d_in[15], d_in[17], d_in[18], d_in[19], d_in[20], d_in[21],
        d_in[23], d_in[25], d_in[27], d_in[29],
        d_in[31], d_in[32], d_in[33], d_in[34], d_in[35]);

    k_conv<<<B / 4, 256, 0, stream>>>();
    k_qkv<<<(B / 16) * 14, 256, 0, stream>>>();
    k_attn<<<B, 256, 0, stream>>>();
    k_lin1ffn<<<B / 4, 256, 0, stream>>>();
    k_gat<<<B, 256, 0, stream>>>(d_out, B);
    k_fc<<<B / 8, 256, 0, stream>>>(d_out, B);
}

// Round 15
// 898.351 us; speedup vs baseline: 1.0400x; 1.0400x over previous
//
#include <hip/hip_runtime.h>
#include <hip/hip_bf16.h>

typedef __hip_bfloat16 bf16;

__device__ __forceinline__ float b2f(bf16 v) { return __bfloat162float(v); }
__device__ __forceinline__ bf16  f2b(float v) { return __float2bfloat16(v); }

__device__ __forceinline__ float ldany(int isbf, const void* p, int i)
{
    return isbf ? b2f(((const bf16*)p)[i]) : ((const float*)p)[i];
}

#define SELU_SCALE 1.0507009873554805f
#define SELU_ALPHA 1.6732632423543772f
#define INV_SQRT2  0.7071067811865475f
#define SELU_F(v) ((v) > 0.f ? SELU_SCALE * (v) : SELU_SCALE * SELU_ALPHA * expm1f(v))

#define NB 2048   // batch (fixed by reference)

// dtype flag + global staging
__device__ int   g_flag;                        // 1 = bf16 tensors, 0 = f32
__device__ float g_xin [(size_t)NB * 310];      // f32 copy of x
__device__ float g_qkv [(size_t)NB * 3348];     // q(744)|k(744)|v(1860) per sample
__device__ float g_x2t [(size_t)NB * 1860];     // attention output (pre-lin1)
__device__ float g_xx1 [(size_t)NB * 1860];     // conv-branch output
__device__ float g_xt  [(size_t)NB * 310];      // transformer output
__device__ float g_x11f[(size_t)NB * 620];      // f32 copy of x11 for k_fc
__device__ float g_L   [3844];                  // normalized Laplacian

// transposed (contraction-contiguous) f32 weights; row strides padded to 16B
__device__ float g_qkvT [(size_t)3348 * 312];   // [o][f] f<310 valid
__device__ float g_lin1T[(size_t)310 * 1860];   // [o][f]
__device__ float g_ffn1T[(size_t)186 * 312];    // [j][f] f<310 valid
__device__ float g_ffn2T[(size_t)310 * 188];    // [o][j] j<186 valid
__device__ float g_fc1T [(size_t)256 * 620];    // [o][f]
__device__ __align__(16) float g_gatW[4480];    // [h][f][o] f32 copy of gat_w
__device__ __align__(16) float g_outW[1280];    // [f][o]    f32 copy of out_w
// conv weights transposed to [(i*K+k)][o] with o padded to 64 (o>=62 -> 0)
#define CW3T_ONE (62 * 3 * 64)                  // 11904
#define CW5T_ONE (62 * 5 * 64)                  // 19840
#define CW3T_SZ  (4 * CW3T_ONE)                 // 47616
#define CW5T_SZ  (3 * CW5T_ONE)                 // 59520
__device__ __align__(16) float g_cwT[CW3T_SZ + CW5T_SZ];

// f32 staged small params
__device__ float g_cb3[248], g_cb5[186], g_bng[434], g_bnb[434];
__device__ float g_caw1[1860], g_caw2[1860];
__device__ float g_qb[744], g_kb[744], g_vb[1860];
__device__ float g_lin1b[310], g_ln1g[5], g_ln1bb[5], g_ln2g[5], g_ln2bb[5];
__device__ float g_ffnb1[186], g_ffnb2[310];
__device__ float g_gata[256], g_outa[20];
__device__ float g_fc1b[256], g_fc2w[8192], g_fc2b[32], g_fc3w[128], g_fc3b[4];

// ---- dtype probe ----
__global__ void k_probe(const void* x0)
{
    __shared__ int cnt;
    if (threadIdx.x == 0) cnt = 0;
    __syncthreads();
    const bf16* p = (const bf16*)x0;
    int bad = 0;
    for (int i = threadIdx.x; i < 4096; i += 256) {
        float v = b2f(p[i]);
        if (!(fabsf(v) < 1e6f)) bad++;
    }
    atomicAdd(&cnt, bad);
    __syncthreads();
    if (threadIdx.x == 0) g_flag = (cnt < 32) ? 1 : 0;
}

// ---- one-time big-array transposes / conversions (runtime dtype branch) ----
#define QKVT_SZ  (3348 * 312)
#define LIN1T_SZ (310 * 1860)
#define FFN1T_SZ (186 * 312)
#define FFN2T_SZ (310 * 188)
#define FC1T_SZ  (256 * 620)
#define GATW_SZ  4480
#define OUTW_SZ  1280
#define XIN_SZ   (NB * 310)
#define WPREP_TOTAL (QKVT_SZ + LIN1T_SZ + FFN1T_SZ + FFN2T_SZ + FC1T_SZ + GATW_SZ + OUTW_SZ + XIN_SZ + CW3T_SZ + CW5T_SZ)

__global__ __launch_bounds__(256) void k_wprep(
    const void* __restrict__ qw, const void* __restrict__ kw, const void* __restrict__ vw,
    const void* __restrict__ lin1_w, const void* __restrict__ ffn_w1, const void* __restrict__ ffn_w2,
    const void* __restrict__ fc1_w, const void* __restrict__ gat_w, const void* __restrict__ out_w,
    const void* __restrict__ x, const void* __restrict__ cw3, const void* __restrict__ cw5)
{
    const int isbf = g_flag;
    int idx = blockIdx.x * 256 + threadIdx.x;
    if (idx >= WPREP_TOTAL) return;
    if (idx < QKVT_SZ) {
        int o = idx / 312, f = idx - o * 312;
        float v = 0.f;
        if (f < 310) {
            if (o < 744)       { int h = o / 124, c = o - h * 124; v = ldany(isbf, qw, h * 38440 + f * 124 + c); }
            else if (o < 1488) { int r = o - 744;  int h = r / 124, c = r - h * 124; v = ldany(isbf, kw, h * 38440 + f * 124 + c); }
            else               { int r = o - 1488; int h = r / 310, c = r - h * 310; v = ldany(isbf, vw, h * 96100 + f * 310 + c); }
        }
        g_qkvT[idx] = v;
        return;
    }
    idx -= QKVT_SZ;
    if (idx < LIN1T_SZ) {
        int o = idx / 1860, f = idx - o * 1860;
        g_lin1T[idx] = ldany(isbf, lin1_w, f * 310 + o);
        return;
    }
    idx -= LIN1T_SZ;
    if (idx < FFN1T_SZ) {
        int j = idx / 312, f = idx - j * 312;
        g_ffn1T[idx] = (f < 310) ? ldany(isbf, ffn_w1, f * 186 + j) : 0.f;
        return;
    }
    idx -= FFN1T_SZ;
    if (idx < FFN2T_SZ) {
        int o = idx / 188, j = idx - o * 188;
        g_ffn2T[idx] = (j < 186) ? ldany(isbf, ffn_w2, j * 310 + o) : 0.f;
        return;
    }
    idx -= FFN2T_SZ;
    if (idx < FC1T_SZ) {
        int o = idx / 620, f = idx - o * 620;
        g_fc1T[idx] = ldany(isbf, fc1_w, f * 256 + o);
        return;
    }
    idx -= FC1T_SZ;
    if (idx < GATW_SZ) { g_gatW[idx] = ldany(isbf, gat_w, idx); return; }
    idx -= GATW_SZ;
    if (idx < OUTW_SZ) { g_outW[idx] = ldany(isbf, out_w, idx); return; }
    idx -= OUTW_SZ;
    if (idx < XIN_SZ) { g_xin[idx] = ldany(isbf, x, idx); return; }
    idx -= XIN_SZ;
    if (idx < CW3T_SZ) {
        int c = idx / CW3T_ONE, r = idx - c * CW3T_ONE;
        int ik = r >> 6, o = r & 63;
        g_cwT[idx] = (o < 62) ? ldany(isbf, cw3, c * 11532 + o * 186 + ik) : 0.f;
        return;
    }
    idx -= CW3T_SZ;
    {
        int c = idx / CW5T_ONE, r = idx - c * CW5T_ONE;
        int ik = r >> 6, o = r & 63;
        g_cwT[CW3T_SZ + idx] = (o < 62) ? ldany(isbf, cw5, c * 19220 + o * 310 + ik) : 0.f;
    }
}

// ---- Laplacian + all small-param conversions (runtime dtype branch) ----
__global__ __launch_bounds__(256) void k_prep(
    const void* __restrict__ A,
    const void* __restrict__ cb3, const void* __restrict__ cb5,
    const void* __restrict__ bn_g, const void* __restrict__ bn_b,
    const void* __restrict__ ca_w1, const void* __restrict__ ca_w2,
    const void* __restrict__ qb, const void* __restrict__ kb, const void* __restrict__ vb,
    const void* __restrict__ lin1_b,
    const void* __restrict__ ln1_g, const void* __restrict__ ln1_b,
    const void* __restrict__ ln2_g, const void* __restrict__ ln2_b,
    const void* __restrict__ ffn_b1, const void* __restrict__ ffn_b2,
    const void* __restrict__ gat_a, const void* __restrict__ out_a,
    const void* __restrict__ fc1_b, const void* __restrict__ fc2_w, const void* __restrict__ fc2_b,
    const void* __restrict__ fc3_w, const void* __restrict__ fc3_b)
{
    const int isbf = g_flag;
    __shared__ float sdinv[62];
    const int tid = threadIdx.x;
    if (blockIdx.x == 0) {
        if (tid < 62) {
            float s = 0.f;
            for (int m = 0; m < 62; ++m) s += fmaxf(ldany(isbf, A, tid * 62 + m), 0.f);
            sdinv[tid] = rsqrtf(s + 1e-10f);
        }
        __syncthreads();
        for (int idx = tid; idx < 3844; idx += 256) {
            int n = idx / 62, m = idx - n * 62;
            g_L[idx] = sdinv[n] * fmaxf(ldany(isbf, A, idx), 0.f) * sdinv[m];
        }
        return;
    }
    int idx = (blockIdx.x - 1) * 256 + tid;
#define CP(dst, src, n) { if (idx < (n)) { dst[idx] = ldany(isbf, src, idx); return; } idx -= (n); }
    CP(g_cb3, cb3, 248) CP(g_cb5, cb5, 186)
    CP(g_bng, bn_g, 434) CP(g_bnb, bn_b, 434)
    CP(g_caw1, ca_w1, 1860) CP(g_caw2, ca_w2, 1860)
    CP(g_qb, qb, 744) CP(g_kb, kb, 744) CP(g_vb, vb, 1860)
    CP(g_lin1b, lin1_b, 310)
    CP(g_ln1g, ln1_g, 5) CP(g_ln1bb, ln1_b, 5) CP(g_ln2g, ln2_g, 5) CP(g_ln2bb, ln2_b, 5)
    CP(g_ffnb1, ffn_b1, 186) CP(g_ffnb2, ffn_b2, 310)
    CP(g_gata, gat_a, 256) CP(g_outa, out_a, 20)
    CP(g_fc1b, fc1_b, 256) CP(g_fc2w, fc2_w, 8192) CP(g_fc2b, fc2_b, 32)
    CP(g_fc3w, fc3_w, 128) CP(g_fc3b, fc3_b, 4)
#undef CP
}

// ================= conv branch, G=4 samples/block (R10-proven) =================
template<int K>
__device__ void conv_g(int tid, const float* sIn, int Lin, int Lout,
                       const float* __restrict__ WT,
                       const float* __restrict__ cb, const float* __restrict__ bng,
                       const float* __restrict__ bnb,
                       float* sOut, int ostride, int ooff)
{
    const float bninv = rsqrtf(1.0f + 1e-5f);
    if (tid < 16 * Lout) {
        int oq = tid / Lout, l = tid - oq * Lout;
        const float* wp = WT + oq * 4;
        float4 c0 = {0,0,0,0}, c1 = {0,0,0,0}, c2 = {0,0,0,0}, c3 = {0,0,0,0};
        #pragma unroll 2
        for (int i = 0; i < 62; ++i) {
            #pragma unroll
            for (int k = 0; k < K; ++k) {
                const float4 w  = *(const float4*)(wp + (i * K + k) * 64);
                const float4 xv = *(const float4*)(sIn + (i * Lin + l + k) * 4);
                c0.x += w.x * xv.x; c0.y += w.x * xv.y; c0.z += w.x * xv.z; c0.w += w.x * xv.w;
                c1.x += w.y * xv.x; c1.y += w.y * xv.y; c1.z += w.y * xv.z; c1.w += w.y * xv.w;
                c2.x += w.z * xv.x; c2.y += w.z * xv.y; c2.z += w.z * xv.z; c2.w += w.z * xv.w;
                c3.x += w.w * xv.x; c3.y += w.w * xv.y; c3.z += w.w * xv.z; c3.w += w.w * xv.w;
            }
        }
        float4 cc[4] = {c0, c1, c2, c3};
        #pragma unroll
        for (int oo = 0; oo < 4; ++oo) {
            int o = oq * 4 + oo;
            if (o < 62) {
                float bias = cb[o], gg = bng[o] * bninv, bb = bnb[o];
                float v0 = (cc[oo].x + bias) * gg + bb;
                float v1 = (cc[oo].y + bias) * gg + bb;
                float v2 = (cc[oo].z + bias) * gg + bb;
                float v3 = (cc[oo].w + bias) * gg + bb;
                float4 r;
                r.x = SELU_F(v0); r.y = SELU_F(v1); r.z = SELU_F(v2); r.w = SELU_F(v3);
                *(float4*)(sOut + (o * ostride + ooff + l) * 4) = r;
            }
        }
    }
    __syncthreads();
}

__device__ void chan_att_g(int tid, float* sIn, int Ls,
                           const float* __restrict__ w1, const float* __restrict__ w2,
                           float* pool, float* hid)
{
    __syncthreads();
    for (int idx = tid; idx < 496; idx += 256) {
        int which = idx >= 248; int r = idx - which * 248;
        int n = r >> 2, g = r & 3;
        float a = 0.f, m = -3.4e38f;
        for (int l = 0; l < Ls; ++l) { float v = sIn[(n * Ls + l) * 4 + g]; a += v; m = fmaxf(m, v); }
        pool[(which * 62 + n) * 4 + g] = which ? m : a / (float)Ls;
    }
    __syncthreads();
    if (tid < 120) {
        int g = tid & 3; int t = tid >> 2;
        int which = t / 15, j = t - which * 15;
        float acc = 0.f;
        for (int n = 0; n < 62; ++n) acc += pool[(which * 62 + n) * 4 + g] * w1[j * 62 + n];
        hid[(which * 16 + j) * 4 + g] = fmaxf(acc, 0.f);
    }
    __syncthreads();
    if (tid < 248) {
        int g = tid & 3, n = tid >> 2;
        float acc = 0.f;
        for (int j = 0; j < 15; ++j) acc += (hid[j * 4 + g] + hid[(16 + j) * 4 + g]) * w2[n * 15 + j];
        float s = 1.f / (1.f + expf(-acc));
        for (int l = 0; l < Ls; ++l) sIn[(n * Ls + l) * 4 + g] *= s;
    }
    __syncthreads();
}

__global__ __launch_bounds__(256) void k_conv()
{
    __shared__ __align__(16) float sx2[496 * 4];
    __shared__ __align__(16) float sbuf[868 * 4];
    __shared__ __align__(16) float sxx1[1860 * 4];
    const int tid = threadIdx.x;
    const int grp = blockIdx.x;
    const float* cw3T = g_cwT;
    const float* cw5T = g_cwT + CW3T_SZ;
    float* spool = sbuf;          // sbuf dead during both chan_att calls
    float* shid  = sbuf + 496;

    for (int idx = tid; idx < 310 * 4; idx += 256) {
        int p = idx >> 2, g = idx & 3; int n = p / 5, c = p - n * 5;
        sx2[(n * 8 + 3 + c) * 4 + g] = g_xin[(size_t)(grp * 4 + g) * 310 + p];
    }
    __syncthreads();

    conv_g<3>(tid, sx2 + 12, 8, 3, cw3T, g_cb3, g_bng, g_bnb, sx2, 8, 0);
    chan_att_g(tid, sx2, 8, g_caw1, g_caw2, spool, shid);

    conv_g<3>(tid, sx2, 8, 6, cw3T + CW3T_ONE, g_cb3 + 62, g_bng + 62, g_bnb + 62, sbuf, 14, 8);
    for (int idx = tid; idx < 496 * 4; idx += 256) {
        int p = idx >> 2, g = idx & 3; int n = p >> 3, c = p & 7;
        sbuf[(n * 14 + c) * 4 + g] = sx2[idx];
    }
    __syncthreads();
    conv_g<3>(tid, sbuf, 14, 12, cw3T + 2 * CW3T_ONE, g_cb3 + 124, g_bng + 124, g_bnb + 124, sxx1, 30, 0);

    conv_g<5>(tid, sx2, 8, 4, cw5T, g_cb5, g_bng + 186, g_bnb + 186, sbuf, 12, 0);
    for (int idx = tid; idx < 496 * 4; idx += 256) {
        int p = idx >> 2, g = idx & 3; int n = p >> 3, c = p & 7;
        sbuf[(n * 12 + 4 + c) * 4 + g] = sx2[idx];
    }
    __syncthreads();
    conv_g<5>(tid, sbuf, 12, 8, cw5T + CW5T_ONE, g_cb5 + 62, g_bng + 248, g_bnb + 248, sxx1, 30, 12);

    conv_g<3>(tid, sx2, 8, 6, cw3T + 3 * CW3T_ONE, g_cb3 + 186, g_bng + 310, g_bnb + 310, sbuf, 14, 0);
    for (int idx = tid; idx < 496 * 4; idx += 256) {
        int p = idx >> 2, g = idx & 3; int n = p >> 3, c = p & 7;
        sbuf[(n * 14 + 6 + c) * 4 + g] = sx2[idx];
    }
    __syncthreads();
    conv_g<5>(tid, sbuf, 14, 10, cw5T + 2 * CW5T_ONE, g_cb5 + 124, g_bng + 372, g_bnb + 372, sxx1, 30, 20);

    chan_att_g(tid, sxx1, 30, g_caw1 + 930, g_caw2 + 930, spool, shid);

    for (int idx = tid; idx < 1860 * 4; idx += 256) {
        int p = idx >> 2, g = idx & 3;
        g_xx1[(size_t)(grp * 4 + g) * 1860 + p] = sxx1[idx];
    }
}

// ================= transformer =================
// QKV GEMM (R11-proven): 16 samples/block, LN1 fused, 2 outputs/thread
__global__ __launch_bounds__(256) void k_qkv()
{
    __shared__ __align__(16) float sxf[310 * 16];
    const int tid = threadIdx.x;
    const int grp = blockIdx.x / 7;
    const int tile = blockIdx.x - grp * 7;

    for (int idx = tid; idx < 310 * 16; idx += 256) {
        int f = idx >> 4, g = idx & 15;
        sxf[idx] = g_xin[(size_t)(grp * 16 + g) * 310 + f];
    }
    __syncthreads();
    // LN1 in place
    for (int it = tid; it < 992; it += 256) {
        int i = it >> 4, g = it & 15;
        float xv[5], m = 0.f, s = 0.f;
        #pragma unroll
        for (int c = 0; c < 5; ++c) { xv[c] = sxf[(i * 5 + c) * 16 + g]; m += xv[c]; s += xv[c] * xv[c]; }
        m *= 0.2f;
        float inv = rsqrtf(fmaxf(s * 0.2f - m * m, 0.f) + 1e-5f);
        #pragma unroll
        for (int c = 0; c < 5; ++c)
            sxf[(i * 5 + c) * 16 + g] = (xv[c] - m) * inv * g_ln1g[c] + g_ln1bb[c];
    }
    __syncthreads();

    int o0 = tile * 512 + tid;
    if (o0 >= 3348) return;
    int o1 = o0 + 256;
    const int valid1 = (o1 < 3348);
    int o1c = valid1 ? o1 : 3347;   // clamp: reads valid memory, result discarded

    float bias0 = (o0 < 744) ? g_qb[o0] : (o0 < 1488) ? g_kb[o0 - 744] : g_vb[o0 - 1488];
    float bias1 = (o1c < 744) ? g_qb[o1c] : (o1c < 1488) ? g_kb[o1c - 744] : g_vb[o1c - 1488];
    const float* W0 = g_qkvT + (size_t)o0 * 312;
    const float* W1 = g_qkvT + (size_t)o1c * 312;

    float accA[16], accB[16];
    #pragma unroll
    for (int g = 0; g < 16; ++g) { accA[g] = bias0; accB[g] = bias1; }

#define QS2(wka, wkb, ff) { \
    const float4* xp = (const float4*)(sxf + (ff) * 16); \
    const float4 x0 = xp[0], x1 = xp[1], x2 = xp[2], x3 = xp[3]; \
    float xs[16]; \
    *(float4*)(xs) = x0; *(float4*)(xs + 4) = x1; *(float4*)(xs + 8) = x2; *(float4*)(xs + 12) = x3; \
    _Pragma("unroll") \
    for (int g = 0; g < 16; ++g) { accA[g] += (wka) * xs[g]; accB[g] += (wkb) * xs[g]; } }

    for (int f = 0; f < 308; f += 4) {
        const float4 wa = *(const float4*)(W0 + f);
        const float4 wb = *(const float4*)(W1 + f);
        QS2(wa.x, wb.x, f) QS2(wa.y, wb.y, f + 1) QS2(wa.z, wb.z, f + 2) QS2(wa.w, wb.w, f + 3)
    }
    QS2(W0[308], W1[308], 308) QS2(W0[309], W1[309], 309)
#undef QS2

    #pragma unroll
    for (int g = 0; g < 16; ++g) {
        size_t base = (size_t)(grp * 16 + g) * 3348;
        g_qkv[base + o0] = accA[g];
        if (valid1) g_qkv[base + o1] = accB[g];
    }
}

// per-sample attention -> g_x2t
// R15: QK^T fused with row-max partials (one pass, q regs hoisted): -3844 LDS
// reads, -1 barrier per head. Max/exp strip partition unchanged -> bit-exact.
__global__ __launch_bounds__(256) void k_attn()
{
    __shared__ float sqkv[3348];
    __shared__ float satt[3844];
    __shared__ float sred[496];
    const int tid = threadIdx.x;
    const int b = blockIdx.x;

    for (int i = tid; i < 3348; i += 256) sqkv[i] = g_qkv[(size_t)b * 3348 + i];
    __syncthreads();

    for (int h = 0; h < 6; ++h) {
        const float* q = sqkv + h * 124;
        const float* k = sqkv + 744 + h * 124;
        float* v = sqkv + 1488 + h * 310;
        // fused QK^T + row-max partials: thread = (j-strip qq, row i)
        if (tid < 248) {
            int qq = tid / 62, i = tid - qq * 62;
            int j0 = qq * 16, j1 = j0 + 16 > 62 ? 62 : j0 + 16;
            float qa = q[i * 2], qb2 = q[i * 2 + 1];
            float* row = satt + i * 62;
            float mx = -3.4e38f;
            for (int j = j0; j < j1; ++j) {
                float s = (qa * k[j * 2] + qb2 * k[j * 2 + 1]) * INV_SQRT2;
                row[j] = s;
                mx = fmaxf(mx, s);
            }
            sred[qq * 62 + i] = mx;
        }
        __syncthreads();
        // exp + row-sum partials
        if (tid < 248) {
            int qq = tid / 62, i = tid - qq * 62;
            int j0 = qq * 16, j1 = j0 + 16 > 62 ? 62 : j0 + 16;
            float rmx = fmaxf(fmaxf(sred[i], sred[62 + i]), fmaxf(sred[124 + i], sred[186 + i]));
            float* row = satt + i * 62;
            float s = 0.f;
            for (int j = j0; j < j1; ++j) { float e = expf(row[j] - rmx); row[j] = e; s += e; }
            sred[248 + qq * 62 + i] = s;
        }
        __syncthreads();
        // one rcp per row
        if (tid < 62)
            sred[tid] = 1.f / (sred[248 + tid] + sred[310 + tid] + sred[372 + tid] + sred[434 + tid]);
        __syncthreads();
        // fold inv into v rows once (PV stays 2-read)
        for (int t = tid; t < 310; t += 256) v[t] *= sred[t / 5];
        __syncthreads();
        for (int idx = tid; idx < 310; idx += 256) {
            int i = idx / 5, c = idx - i * 5;
            float acc = 0.f;
            for (int j = 0; j < 62; ++j) acc += satt[j * 62 + i] * v[j * 5 + c];
            g_x2t[(size_t)b * 1860 + i * 30 + h * 5 + c] = acc;
        }
        __syncthreads();
    }
}

// lin1 + residual + LN2 + FFN + residual (R11/R6-proven body)
__global__ __launch_bounds__(256) void k_lin1ffn()
{
    __shared__ __align__(16) float sx2t[1860 * 4];
    __shared__ __align__(16) float sX[310 * 4];
    __shared__ __align__(16) float sx21[310 * 4];
    __shared__ __align__(16) float sxf[310 * 4];
    __shared__ __align__(16) float shg[186 * 4];
    __shared__ __align__(16) float spart[620 * 4];
    const int tid = threadIdx.x;
    const int grp = blockIdx.x;

    for (int idx = tid; idx < 1860 * 4; idx += 256) {
        int f = idx >> 2, g = idx & 3;
        sx2t[idx] = g_x2t[(size_t)(grp * 4 + g) * 1860 + f];
    }
    for (int idx = tid; idx < 310 * 4; idx += 256) {
        int o = idx >> 2, g = idx & 3;
        sX[idx] = g_xin[(size_t)(grp * 4 + g) * 310 + o];
    }
    __syncthreads();

#define XSTEP(wk, ff, Xb) { const float4 xv = *(const float4*)((Xb) + (ff) * 4); \
                            a0 += (wk) * xv.x; a1 += (wk) * xv.y; a2 += (wk) * xv.z; a3 += (wk) * xv.w; }
    for (int item = tid; item < 620; item += 256) {
        int half = item >= 310; int o = item - half * 310;
        int fbase = half ? 928 : 0;
        int fcnt = half ? 932 : 928;
        const float* W = g_lin1T + (size_t)o * 1860 + fbase;
        const float* Xb = sx2t + fbase * 4;
        float a0 = 0.f, a1 = 0.f, a2 = 0.f, a3 = 0.f;
        for (int f = 0; f < fcnt; f += 4) {
            const float4 w = *(const float4*)(W + f);
            XSTEP(w.x, f, Xb) XSTEP(w.y, f + 1, Xb) XSTEP(w.z, f + 2, Xb) XSTEP(w.w, f + 3, Xb)
        }
        spart[item * 4 + 0] = a0; spart[item * 4 + 1] = a1;
        spart[item * 4 + 2] = a2; spart[item * 4 + 3] = a3;
    }
    __syncthreads();
    for (int o = tid; o < 310; o += 256) {
        float bias = g_lin1b[o];
        for (int g = 0; g < 4; ++g)
            sx21[o * 4 + g] = spart[o * 4 + g] + spart[(310 + o) * 4 + g] + bias + sX[o * 4 + g];
    }
    __syncthreads();

    if (tid < 248) {
        int i = tid >> 2, g = tid & 3;
        float m = 0.f, s = 0.f;
        for (int c = 0; c < 5; ++c) { float v = sx21[(i * 5 + c) * 4 + g]; m += v; s += v * v; }
        m *= 0.2f;
        float inv = rsqrtf(fmaxf(s * 0.2f - m * m, 0.f) + 1e-5f);
        for (int c = 0; c < 5; ++c)
            sxf[(i * 5 + c) * 4 + g] = (sx21[(i * 5 + c) * 4 + g] - m) * inv * g_ln2g[c] + g_ln2bb[c];
    }
    __syncthreads();

    if (tid < 186) {
        const float* W = g_ffn1T + (size_t)tid * 312;
        float bias = g_ffnb1[tid];
        float a0 = bias, a1 = bias, a2 = bias, a3 = bias;
        for (int f = 0; f < 308; f += 4) {
            const float4 w = *(const float4*)(W + f);
            XSTEP(w.x, f, sxf) XSTEP(w.y, f + 1, sxf) XSTEP(w.z, f + 2, sxf) XSTEP(w.w, f + 3, sxf)
        }
        XSTEP(W[308], 308, sxf) XSTEP(W[309], 309, sxf)
        shg[tid * 4 + 0] = 0.5f * a0 * (1.f + erff(a0 * INV_SQRT2));
        shg[tid * 4 + 1] = 0.5f * a1 * (1.f + erff(a1 * INV_SQRT2));
        shg[tid * 4 + 2] = 0.5f * a2 * (1.f + erff(a2 * INV_SQRT2));
        shg[tid * 4 + 3] = 0.5f * a3 * (1.f + erff(a3 * INV_SQRT2));
    }
    __syncthreads();

    for (int o = tid; o < 310; o += 256) {
        const float* W = g_ffn2T + (size_t)o * 188;
        float bias = g_ffnb2[o];
        float a0 = bias, a1 = bias, a2 = bias, a3 = bias;
        for (int j = 0; j < 184; j += 4) {
            const float4 w = *(const float4*)(W + j);
            XSTEP(w.x, j, shg) XSTEP(w.y, j + 1, shg) XSTEP(w.z, j + 2, shg) XSTEP(w.w, j + 3, shg)
        }
        XSTEP(W[184], 184, shg) XSTEP(W[185], 185, shg)
        g_xt[(size_t)(grp * 4 + 0) * 310 + o] = a0 + sx21[o * 4 + 0];
        g_xt[(size_t)(grp * 4 + 1) * 310 + o] = a1 + sx21[o * 4 + 1];
        g_xt[(size_t)(grp * 4 + 2) * 310 + o] = a2 + sx21[o * 4 + 2];
        g_xt[(size_t)(grp * 4 + 3) * 310 + o] = a3 + sx21[o * 4 + 3];
    }
#undef XSTEP
}

// ================= GAT (R9-proven: fold passes + register layer-2 accum) =================
__global__ __launch_bounds__(256) void k_gat(void* __restrict__ out, int B)
{
    __shared__ __align__(16) float satt[3844];
    __shared__ __align__(16) float sh[1984];
    __shared__ __align__(16) float sbufA[2170];   // layer1: f32 sxx; layer2: soutg
    __shared__ float ssrc[124];
    __shared__ float sred[496];
    __shared__ float sacc2[620];
    const int tid = threadIdx.x;
    const int b = blockIdx.x;
    const int isbf = g_flag;
    float* sxx = sbufA;

    for (int idx = tid; idx < 2170; idx += 256) {
        int n = idx / 35, f = idx - n * 35;
        sxx[idx] = (f < 30) ? g_xx1[(size_t)b * 1860 + n * 30 + f]
                            : g_xt[(size_t)b * 310 + n * 5 + (f - 30)];
    }

    float racc0[10], racc1[10];
    #pragma unroll
    for (int o = 0; o < 10; ++o) { racc0[o] = 0.f; racc1[o] = 0.f; }

    for (int h = 0; h < 4; ++h) {
        for (int idx = tid; idx < 1120; idx += 256) satt[idx] = g_gatW[h * 1120 + idx];
        __syncthreads();
        float* sp1 = satt + 1200;
        float* sp2 = satt + 1800;
        for (int item = tid; item < 496; item += 256) {
            int n = item >> 3, oqi = item & 7, oq = oqi * 4;
            const float* xr = sxx + n * 35;
            float a0 = 0.f, a1 = 0.f, a2 = 0.f, a3 = 0.f;
            for (int f = 0; f < 35; ++f) {
                float xv = xr[f];
                const float4 w = *(const float4*)(satt + f * 32 + oq);
                a0 += xv * w.x; a1 += xv * w.y; a2 += xv * w.z; a3 += xv * w.w;
            }
            float4 r; r.x = a0; r.y = a1; r.z = a2; r.w = a3;
            *(float4*)(sh + n * 32 + oq) = r;
            float l0 = a0 > 0.f ? a0 : 0.2f * a0;
            float l1 = a1 > 0.f ? a1 : 0.2f * a1;
            float l2 = a2 > 0.f ? a2 : 0.2f * a2;
            float l3 = a3 > 0.f ? a3 : 0.2f * a3;
            const float* ga = g_gata + h * 64 + oq;
            sp1[n * 9 + oqi] = l0 * ga[0] + l1 * ga[1] + l2 * ga[2] + l3 * ga[3];
            sp2[n * 9 + oqi] = l0 * ga[32] + l1 * ga[33] + l2 * ga[34] + l3 * ga[35];
        }
        __syncthreads();
        if (tid < 124) {
            int which = tid >= 62; int n = tid - which * 62;
            const float* pp = which ? sp2 : sp1;
            float s = 0.f;
            for (int q = 0; q < 8; ++q) s += pp[n * 9 + q];
            ssrc[tid] = s;
        }
        __syncthreads();
        if (tid < 248) {
            int q = tid / 62, m = tid - q * 62;
            int n0 = q * 16, n1 = n0 + 16 > 62 ? 62 : n0 + 16;
            float s2m = ssrc[62 + m];
            float mx = -3.4e38f;
            for (int n = n0; n < n1; ++n) {
                float dj = 0.8f * g_L[n * 62 + m] + 0.2f * (ssrc[n] + s2m);
                dj = dj > 0.f ? dj : -1e12f;
                satt[n * 62 + m] = dj;
                mx = fmaxf(mx, dj);
            }
            sred[q * 62 + m] = mx;
        }
        __syncthreads();
        if (tid < 248) {
            int q = tid / 62, m = tid - q * 62;
            int n0 = q * 16, n1 = n0 + 16 > 62 ? 62 : n0 + 16;
            float cmx = fmaxf(fmaxf(sred[m], sred[62 + m]), fmaxf(sred[124 + m], sred[186 + m]));
            float s = 0.f;
            for (int n = n0; n < n1; ++n) {
                float e = expf(satt[n * 62 + m] - cmx);
                satt[n * 62 + m] = e;
                s += e;
            }
            sred[248 + q * 62 + m] = s;
        }
        __syncthreads();
        if (tid < 62)
            ssrc[tid] = 1.f / (sred[248 + tid] + sred[310 + tid] + sred[372 + tid] + sred[434 + tid]);
        __syncthreads();
        for (int item = tid; item < 1984; item += 256) sh[item] *= ssrc[item >> 5];
        __syncthreads();
        if (tid < 248) {
            int ip = tid >> 3, oqi = tid & 7, oq = oqi * 4;
            int i0 = ip * 2;
            const float* ar0 = satt + i0 * 62;
            const float* ar1 = ar0 + 62;
            float a00 = 0.f, a01 = 0.f, a02 = 0.f, a03 = 0.f;
            float a10 = 0.f, a11 = 0.f, a12 = 0.f, a13 = 0.f;
            for (int j = 0; j < 62; ++j) {
                const float4 hv = *(const float4*)(sh + j * 32 + oq);
                float v0 = ar0[j], v1 = ar1[j];
                a00 += v0 * hv.x; a01 += v0 * hv.y; a02 += v0 * hv.z; a03 += v0 * hv.w;
                a10 += v1 * hv.x; a11 += v1 * hv.y; a12 += v1 * hv.z; a13 += v1 * hv.w;
            }
            a00 = fmaxf(a00, 0.f); a01 = fmaxf(a01, 0.f); a02 = fmaxf(a02, 0.f); a03 = fmaxf(a03, 0.f);
            a10 = fmaxf(a10, 0.f); a11 = fmaxf(a11, 0.f); a12 = fmaxf(a12, 0.f); a13 = fmaxf(a13, 0.f);
            const float* W2 = g_outW + (h * 32 + oq) * 10;
            #pragma unroll
            for (int o = 0; o < 10; ++o) {
                float w0 = W2[o], w1 = W2[10 + o], w2c = W2[20 + o], w3 = W2[30 + o];
                racc0[o] += a00 * w0 + a01 * w1 + a02 * w2c + a03 * w3;
                racc1[o] += a10 * w0 + a11 * w1 + a12 * w2c + a13 * w3;
            }
        }
        __syncthreads();
    }

    if (tid < 248) {
        float* dst = satt + tid * 20;
        #pragma unroll
        for (int o = 0; o < 10; ++o) { dst[o] = racc0[o]; dst[10 + o] = racc1[o]; }
    }
    __syncthreads();
    for (int idx = tid; idx < 620; idx += 256) {
        int i = idx / 10, o = idx - i * 10;
        int ip = i >> 1, half = i & 1;
        const float* src = satt + (ip * 8) * 20 + half * 10 + o;
        float s = 0.f;
        #pragma unroll
        for (int q = 0; q < 8; ++q) s += src[q * 20];
        sacc2[idx] = s;
    }
    __syncthreads();

    float* sh2   = sacc2;
    float* soutg = sbufA;

    if (tid < 124) {
        int which = tid >= 62; int n = tid - which * 62;
        float acc = 0.f;
        for (int o = 0; o < 10; ++o) {
            float v = sh2[n * 10 + o]; v = v > 0.f ? v : 0.2f * v;
            acc += v * g_outa[which * 10 + o];
        }
        ssrc[tid] = acc;
    }
    __syncthreads();
    if (tid < 248) {
        int q = tid / 62, m = tid - q * 62;
        int n0 = q * 16, n1 = n0 + 16 > 62 ? 62 : n0 + 16;
        float s2m = ssrc[62 + m];
        float mx = -3.4e38f;
        for (int n = n0; n < n1; ++n) {
            float dj = 0.8f * g_L[n * 62 + m] + 0.2f * (ssrc[n] + s2m);
            dj = dj > 0.f ? dj : -1e12f;
            satt[n * 62 + m] = dj;
            mx = fmaxf(mx, dj);
        }
        sred[q * 62 + m] = mx;
    }
    __syncthreads();
    if (tid < 248) {
        int q = tid / 62, m = tid - q * 62;
        int n0 = q * 16, n1 = n0 + 16 > 62 ? 62 : n0 + 16;
        float cmx = fmaxf(fmaxf(sred[m], sred[62 + m]), fmaxf(sred[124 + m], sred[186 + m]));
        float s = 0.f;
        for (int n = n0; n < n1; ++n) {
            float e = expf(satt[n * 62 + m] - cmx);
            satt[n * 62 + m] = e;
            s += e;
        }
        sred[248 + q * 62 + m] = s;
    }
    __syncthreads();
    if (tid < 62)
        ssrc[tid] = 1.f / (sred[248 + tid] + sred[310 + tid] + sred[372 + tid] + sred[434 + tid]);
    __syncthreads();
    for (int item = tid; item < 620; item += 256) sh2[item] *= ssrc[item / 10];
    __syncthreads();
    for (int idx = tid; idx < 620; idx += 256) {
        int i = idx / 10, o = idx - i * 10;
        const float* ar = satt + i * 62;
        float acc = 0.f;
        for (int j = 0; j < 62; ++j) acc += ar[j] * sh2[j * 10 + o];
        soutg[idx] = fmaxf(acc, 0.f);
    }
    __syncthreads();

    if (tid < 62) {
        const float* r = soutg + tid * 10;
        float e[10]; float mx = -3.4e38f;
        for (int o = 0; o < 10; ++o) { float v = r[o]; v = v > 0.f ? v : expm1f(v); e[o] = v; mx = fmaxf(mx, v); }
        float sum = 0.f;
        for (int o = 0; o < 10; ++o) sum += expf(e[o] - mx);
        float ls = logf(sum) + mx;
        for (int o = 0; o < 10; ++o) {
            float v = e[o] - ls;
            size_t off = (size_t)b * 620 + tid * 10 + o;
            if (isbf) ((bf16*)out)[off] = f2b(v); else ((float*)out)[off] = v;
            g_x11f[off] = v;
        }
    }
}

// fc1->fc2->fc3 tail, 8 samples/block (R6-proven)
__global__ __launch_bounds__(256) void k_fc(void* __restrict__ out, int B)
{
    __shared__ __align__(16) float sxf[620 * 8];
    __shared__ __align__(16) float st1[256 * 8];
    __shared__ __align__(16) float st2[32 * 8];
    const int tid = threadIdx.x;
    const int grp = blockIdx.x;
    const int isbf = g_flag;

    for (int idx = tid; idx < 620 * 8; idx += 256) {
        int f = idx >> 3, g = idx & 7;
        sxf[idx] = g_x11f[(size_t)(grp * 8 + g) * 620 + f];
    }
    __syncthreads();

    {
        const float* W = g_fc1T + (size_t)tid * 620;
        float bias = g_fc1b[tid];
        float a0 = bias, a1 = bias, a2 = bias, a3 = bias, a4 = bias, a5 = bias, a6 = bias, a7 = bias;
#define FSTEP(wk, ff) { const float4 p = *(const float4*)(sxf + (ff) * 8); \
                        const float4 qq = *(const float4*)(sxf + (ff) * 8 + 4); \
                        a0 += (wk) * p.x; a1 += (wk) * p.y; a2 += (wk) * p.z; a3 += (wk) * p.w; \
                        a4 += (wk) * qq.x; a5 += (wk) * qq.y; a6 += (wk) * qq.z; a7 += (wk) * qq.w; }
        for (int f = 0; f < 620; f += 4) {
            const float4 w = *(const float4*)(W + f);
            FSTEP(w.x, f) FSTEP(w.y, f + 1) FSTEP(w.z, f + 2) FSTEP(w.w, f + 3)
        }
#undef FSTEP
        float4 r0; r0.x = a0; r0.y = a1; r0.z = a2; r0.w = a3;
        float4 r1; r1.x = a4; r1.y = a5; r1.z = a6; r1.w = a7;
        *(float4*)(st1 + tid * 8)     = r0;
        *(float4*)(st1 + tid * 8 + 4) = r1;
    }
    __syncthreads();
    {
        int g = tid >> 5, o = tid & 31;
        float acc = g_fc2b[o];
        for (int f = 0; f < 256; ++f) acc += st1[f * 8 + g] * g_fc2w[f * 32 + o];
        st2[o * 8 + g] = acc;
    }
    __syncthreads();
    if (tid < 32) {
        int g = tid >> 2, o = tid & 3;
        float acc = g_fc3b[o];
        for (int f = 0; f < 32; ++f) acc += st2[f * 8 + g] * g_fc3w[f * 4 + o];
        size_t off = (size_t)B * 620 + (size_t)(grp * 8 + g) * 4 + o;
        if (isbf) ((bf16*)out)[off] = f2b(acc); else ((float*)out)[off] = acc;
    }
}

extern "C" void kernel_launch(void* const* d_in, const int* in_sizes, int n_in,
                              void* d_out, int out_size, void* d_ws, size_t ws_size,
                              hipStream_t stream)
{
    const int B = in_sizes[0] / 310;   // 2048
    const int wprep_blocks = (WPREP_TOTAL + 255) / 256;

    k_probe<<<1, 256, 0, stream>>>(d_in[0]);

    k_wprep<<<wprep_blocks, 256, 0, stream>>>(
        d_in[10], d_in[12], d_in[14], d_in[16], d_in[22], d_in[24], d_in[30],
        d_in[26], d_in[28], d_in[0], d_in[2], d_in[4]);
    k_prep<<<72, 256, 0, stream>>>(
        d_in[1], d_in[3], d_in[5], d_in[6], d_in[7], d_in[8], d_in[9],
        d_in[11], d_in[13], d_in[15], d_in[17], d_in[18], d_in[19], d_in[20], d_in[21],
        d_in[23], d_in[25], d_in[27], d_in[29],
        d_in[31], d_in[32], d_in[33], d_in[34], d_in[35]);

    k_conv<<<B / 4, 256, 0, stream>>>();
    k_qkv<<<(B / 16) * 7, 256, 0, stream>>>();
    k_attn<<<B, 256, 0, stream>>>();
    k_lin1ffn<<<B / 4, 256, 0, stream>>>();
    k_gat<<<B, 256, 0, stream>>>(d_out, B);
    k_fc<<<B / 8, 256, 0, stream>>>(d_out, B);
}

// Round 16
// 891.940 us; speedup vs baseline: 1.0475x; 1.0072x over previous
//
#include <hip/hip_runtime.h>
#include <hip/hip_bf16.h>

typedef __hip_bfloat16 bf16;

__device__ __forceinline__ float b2f(bf16 v) { return __bfloat162float(v); }
__device__ __forceinline__ bf16  f2b(float v) { return __float2bfloat16(v); }

__device__ __forceinline__ float ldany(int isbf, const void* p, int i)
{
    return isbf ? b2f(((const bf16*)p)[i]) : ((const float*)p)[i];
}

#define SELU_SCALE 1.0507009873554805f
#define SELU_ALPHA 1.6732632423543772f
#define INV_SQRT2  0.7071067811865475f
#define SELU_F(v) ((v) > 0.f ? SELU_SCALE * (v) : SELU_SCALE * SELU_ALPHA * expm1f(v))

#define NB 2048   // batch (fixed by reference)

// dtype flag + global staging
__device__ int   g_flag;                        // 1 = bf16 tensors, 0 = f32
__device__ float g_xin [(size_t)NB * 310];      // f32 copy of x
__device__ float g_qkv [(size_t)NB * 3348];     // q(744)|k(744)|v(1860) per sample
__device__ float g_x2t [(size_t)NB * 1860];     // attention output (pre-lin1)
__device__ float g_xx1 [(size_t)NB * 1860];     // conv-branch output
__device__ float g_xt  [(size_t)NB * 310];      // transformer output
__device__ float g_x11f[(size_t)NB * 620];      // f32 copy of x11 for k_fc
__device__ float g_L   [3844];                  // normalized Laplacian

// transposed (contraction-contiguous) f32 weights; row strides padded to 16B
__device__ float g_qkvT [(size_t)3348 * 312];   // [o][f] f<310 valid
__device__ float g_lin1T[(size_t)310 * 1860];   // [o][f]
__device__ float g_ffn1T[(size_t)186 * 312];    // [j][f] f<310 valid
__device__ float g_ffn2T[(size_t)310 * 188];    // [o][j] j<186 valid
__device__ float g_fc1T [(size_t)256 * 620];    // [o][f]
__device__ __align__(16) float g_gatW[4480];    // [h][f][o] f32 copy of gat_w
__device__ __align__(16) float g_outW[1280];    // [f][o]    f32 copy of out_w
// conv weights transposed to [(i*K+k)][o] with o padded to 64 (o>=62 -> 0)
#define CW3T_ONE (62 * 3 * 64)                  // 11904
#define CW5T_ONE (62 * 5 * 64)                  // 19840
#define CW3T_SZ  (4 * CW3T_ONE)                 // 47616
#define CW5T_SZ  (3 * CW5T_ONE)                 // 59520
__device__ __align__(16) float g_cwT[CW3T_SZ + CW5T_SZ];

// f32 staged small params
__device__ float g_cb3[248], g_cb5[186], g_bng[434], g_bnb[434];
__device__ float g_caw1[1860], g_caw2[1860];
__device__ float g_qb[744], g_kb[744], g_vb[1860];
__device__ float g_lin1b[310], g_ln1g[5], g_ln1bb[5], g_ln2g[5], g_ln2bb[5];
__device__ float g_ffnb1[186], g_ffnb2[310];
__device__ float g_gata[256], g_outa[20];
__device__ float g_fc1b[256], g_fc2w[8192], g_fc2b[32], g_fc3w[128], g_fc3b[4];

// ---- dtype probe ----
__global__ void k_probe(const void* x0)
{
    __shared__ int cnt;
    if (threadIdx.x == 0) cnt = 0;
    __syncthreads();
    const bf16* p = (const bf16*)x0;
    int bad = 0;
    for (int i = threadIdx.x; i < 4096; i += 256) {
        float v = b2f(p[i]);
        if (!(fabsf(v) < 1e6f)) bad++;
    }
    atomicAdd(&cnt, bad);
    __syncthreads();
    if (threadIdx.x == 0) g_flag = (cnt < 32) ? 1 : 0;
}

// ---- one-time big-array transposes / conversions (runtime dtype branch) ----
#define QKVT_SZ  (3348 * 312)
#define LIN1T_SZ (310 * 1860)
#define FFN1T_SZ (186 * 312)
#define FFN2T_SZ (310 * 188)
#define FC1T_SZ  (256 * 620)
#define GATW_SZ  4480
#define OUTW_SZ  1280
#define XIN_SZ   (NB * 310)
#define WPREP_TOTAL (QKVT_SZ + LIN1T_SZ + FFN1T_SZ + FFN2T_SZ + FC1T_SZ + GATW_SZ + OUTW_SZ + XIN_SZ + CW3T_SZ + CW5T_SZ)

__global__ __launch_bounds__(256) void k_wprep(
    const void* __restrict__ qw, const void* __restrict__ kw, const void* __restrict__ vw,
    const void* __restrict__ lin1_w, const void* __restrict__ ffn_w1, const void* __restrict__ ffn_w2,
    const void* __restrict__ fc1_w, const void* __restrict__ gat_w, const void* __restrict__ out_w,
    const void* __restrict__ x, const void* __restrict__ cw3, const void* __restrict__ cw5)
{
    const int isbf = g_flag;
    int idx = blockIdx.x * 256 + threadIdx.x;
    if (idx >= WPREP_TOTAL) return;
    if (idx < QKVT_SZ) {
        int o = idx / 312, f = idx - o * 312;
        float v = 0.f;
        if (f < 310) {
            if (o < 744)       { int h = o / 124, c = o - h * 124; v = ldany(isbf, qw, h * 38440 + f * 124 + c); }
            else if (o < 1488) { int r = o - 744;  int h = r / 124, c = r - h * 124; v = ldany(isbf, kw, h * 38440 + f * 124 + c); }
            else               { int r = o - 1488; int h = r / 310, c = r - h * 310; v = ldany(isbf, vw, h * 96100 + f * 310 + c); }
        }
        g_qkvT[idx] = v;
        return;
    }
    idx -= QKVT_SZ;
    if (idx < LIN1T_SZ) {
        int o = idx / 1860, f = idx - o * 1860;
        g_lin1T[idx] = ldany(isbf, lin1_w, f * 310 + o);
        return;
    }
    idx -= LIN1T_SZ;
    if (idx < FFN1T_SZ) {
        int j = idx / 312, f = idx - j * 312;
        g_ffn1T[idx] = (f < 310) ? ldany(isbf, ffn_w1, f * 186 + j) : 0.f;
        return;
    }
    idx -= FFN1T_SZ;
    if (idx < FFN2T_SZ) {
        int o = idx / 188, j = idx - o * 188;
        g_ffn2T[idx] = (j < 186) ? ldany(isbf, ffn_w2, j * 310 + o) : 0.f;
        return;
    }
    idx -= FFN2T_SZ;
    if (idx < FC1T_SZ) {
        int o = idx / 620, f = idx - o * 620;
        g_fc1T[idx] = ldany(isbf, fc1_w, f * 256 + o);
        return;
    }
    idx -= FC1T_SZ;
    if (idx < GATW_SZ) { g_gatW[idx] = ldany(isbf, gat_w, idx); return; }
    idx -= GATW_SZ;
    if (idx < OUTW_SZ) { g_outW[idx] = ldany(isbf, out_w, idx); return; }
    idx -= OUTW_SZ;
    if (idx < XIN_SZ) { g_xin[idx] = ldany(isbf, x, idx); return; }
    idx -= XIN_SZ;
    if (idx < CW3T_SZ) {
        int c = idx / CW3T_ONE, r = idx - c * CW3T_ONE;
        int ik = r >> 6, o = r & 63;
        g_cwT[idx] = (o < 62) ? ldany(isbf, cw3, c * 11532 + o * 186 + ik) : 0.f;
        return;
    }
    idx -= CW3T_SZ;
    {
        int c = idx / CW5T_ONE, r = idx - c * CW5T_ONE;
        int ik = r >> 6, o = r & 63;
        g_cwT[CW3T_SZ + idx] = (o < 62) ? ldany(isbf, cw5, c * 19220 + o * 310 + ik) : 0.f;
    }
}

// ---- Laplacian + all small-param conversions (runtime dtype branch) ----
__global__ __launch_bounds__(256) void k_prep(
    const void* __restrict__ A,
    const void* __restrict__ cb3, const void* __restrict__ cb5,
    const void* __restrict__ bn_g, const void* __restrict__ bn_b,
    const void* __restrict__ ca_w1, const void* __restrict__ ca_w2,
    const void* __restrict__ qb, const void* __restrict__ kb, const void* __restrict__ vb,
    const void* __restrict__ lin1_b,
    const void* __restrict__ ln1_g, const void* __restrict__ ln1_b,
    const void* __restrict__ ln2_g, const void* __restrict__ ln2_b,
    const void* __restrict__ ffn_b1, const void* __restrict__ ffn_b2,
    const void* __restrict__ gat_a, const void* __restrict__ out_a,
    const void* __restrict__ fc1_b, const void* __restrict__ fc2_w, const void* __restrict__ fc2_b,
    const void* __restrict__ fc3_w, const void* __restrict__ fc3_b)
{
    const int isbf = g_flag;
    __shared__ float sdinv[62];
    const int tid = threadIdx.x;
    if (blockIdx.x == 0) {
        if (tid < 62) {
            float s = 0.f;
            for (int m = 0; m < 62; ++m) s += fmaxf(ldany(isbf, A, tid * 62 + m), 0.f);
            sdinv[tid] = rsqrtf(s + 1e-10f);
        }
        __syncthreads();
        for (int idx = tid; idx < 3844; idx += 256) {
            int n = idx / 62, m = idx - n * 62;
            g_L[idx] = sdinv[n] * fmaxf(ldany(isbf, A, idx), 0.f) * sdinv[m];
        }
        return;
    }
    int idx = (blockIdx.x - 1) * 256 + tid;
#define CP(dst, src, n) { if (idx < (n)) { dst[idx] = ldany(isbf, src, idx); return; } idx -= (n); }
    CP(g_cb3, cb3, 248) CP(g_cb5, cb5, 186)
    CP(g_bng, bn_g, 434) CP(g_bnb, bn_b, 434)
    CP(g_caw1, ca_w1, 1860) CP(g_caw2, ca_w2, 1860)
    CP(g_qb, qb, 744) CP(g_kb, kb, 744) CP(g_vb, vb, 1860)
    CP(g_lin1b, lin1_b, 310)
    CP(g_ln1g, ln1_g, 5) CP(g_ln1bb, ln1_b, 5) CP(g_ln2g, ln2_g, 5) CP(g_ln2bb, ln2_b, 5)
    CP(g_ffnb1, ffn_b1, 186) CP(g_ffnb2, ffn_b2, 310)
    CP(g_gata, gat_a, 256) CP(g_outa, out_a, 20)
    CP(g_fc1b, fc1_b, 256) CP(g_fc2w, fc2_w, 8192) CP(g_fc2b, fc2_b, 32)
    CP(g_fc3w, fc3_w, 128) CP(g_fc3b, fc3_b, 4)
#undef CP
}

// ================= conv branch, G=4 samples/block (R10-proven) =================
template<int K>
__device__ void conv_g(int tid, const float* sIn, int Lin, int Lout,
                       const float* __restrict__ WT,
                       const float* __restrict__ cb, const float* __restrict__ bng,
                       const float* __restrict__ bnb,
                       float* sOut, int ostride, int ooff)
{
    const float bninv = rsqrtf(1.0f + 1e-5f);
    if (tid < 16 * Lout) {
        int oq = tid / Lout, l = tid - oq * Lout;
        const float* wp = WT + oq * 4;
        float4 c0 = {0,0,0,0}, c1 = {0,0,0,0}, c2 = {0,0,0,0}, c3 = {0,0,0,0};
        #pragma unroll 2
        for (int i = 0; i < 62; ++i) {
            #pragma unroll
            for (int k = 0; k < K; ++k) {
                const float4 w  = *(const float4*)(wp + (i * K + k) * 64);
                const float4 xv = *(const float4*)(sIn + (i * Lin + l + k) * 4);
                c0.x += w.x * xv.x; c0.y += w.x * xv.y; c0.z += w.x * xv.z; c0.w += w.x * xv.w;
                c1.x += w.y * xv.x; c1.y += w.y * xv.y; c1.z += w.y * xv.z; c1.w += w.y * xv.w;
                c2.x += w.z * xv.x; c2.y += w.z * xv.y; c2.z += w.z * xv.z; c2.w += w.z * xv.w;
                c3.x += w.w * xv.x; c3.y += w.w * xv.y; c3.z += w.w * xv.z; c3.w += w.w * xv.w;
            }
        }
        float4 cc[4] = {c0, c1, c2, c3};
        #pragma unroll
        for (int oo = 0; oo < 4; ++oo) {
            int o = oq * 4 + oo;
            if (o < 62) {
                float bias = cb[o], gg = bng[o] * bninv, bb = bnb[o];
                float v0 = (cc[oo].x + bias) * gg + bb;
                float v1 = (cc[oo].y + bias) * gg + bb;
                float v2 = (cc[oo].z + bias) * gg + bb;
                float v3 = (cc[oo].w + bias) * gg + bb;
                float4 r;
                r.x = SELU_F(v0); r.y = SELU_F(v1); r.z = SELU_F(v2); r.w = SELU_F(v3);
                *(float4*)(sOut + (o * ostride + ooff + l) * 4) = r;
            }
        }
    }
    __syncthreads();
}

__device__ void chan_att_g(int tid, float* sIn, int Ls,
                           const float* __restrict__ w1, const float* __restrict__ w2,
                           float* pool, float* hid)
{
    __syncthreads();
    for (int idx = tid; idx < 496; idx += 256) {
        int which = idx >= 248; int r = idx - which * 248;
        int n = r >> 2, g = r & 3;
        float a = 0.f, m = -3.4e38f;
        for (int l = 0; l < Ls; ++l) { float v = sIn[(n * Ls + l) * 4 + g]; a += v; m = fmaxf(m, v); }
        pool[(which * 62 + n) * 4 + g] = which ? m : a / (float)Ls;
    }
    __syncthreads();
    if (tid < 120) {
        int g = tid & 3; int t = tid >> 2;
        int which = t / 15, j = t - which * 15;
        float acc = 0.f;
        for (int n = 0; n < 62; ++n) acc += pool[(which * 62 + n) * 4 + g] * w1[j * 62 + n];
        hid[(which * 16 + j) * 4 + g] = fmaxf(acc, 0.f);
    }
    __syncthreads();
    if (tid < 248) {
        int g = tid & 3, n = tid >> 2;
        float acc = 0.f;
        for (int j = 0; j < 15; ++j) acc += (hid[j * 4 + g] + hid[(16 + j) * 4 + g]) * w2[n * 15 + j];
        float s = 1.f / (1.f + expf(-acc));
        for (int l = 0; l < Ls; ++l) sIn[(n * Ls + l) * 4 + g] *= s;
    }
    __syncthreads();
}

__global__ __launch_bounds__(256) void k_conv()
{
    __shared__ __align__(16) float sx2[496 * 4];
    __shared__ __align__(16) float sbuf[868 * 4];
    __shared__ __align__(16) float sxx1[1860 * 4];
    const int tid = threadIdx.x;
    const int grp = blockIdx.x;
    const float* cw3T = g_cwT;
    const float* cw5T = g_cwT + CW3T_SZ;
    float* spool = sbuf;          // sbuf dead during both chan_att calls
    float* shid  = sbuf + 496;

    for (int idx = tid; idx < 310 * 4; idx += 256) {
        int p = idx >> 2, g = idx & 3; int n = p / 5, c = p - n * 5;
        sx2[(n * 8 + 3 + c) * 4 + g] = g_xin[(size_t)(grp * 4 + g) * 310 + p];
    }
    __syncthreads();

    conv_g<3>(tid, sx2 + 12, 8, 3, cw3T, g_cb3, g_bng, g_bnb, sx2, 8, 0);
    chan_att_g(tid, sx2, 8, g_caw1, g_caw2, spool, shid);

    conv_g<3>(tid, sx2, 8, 6, cw3T + CW3T_ONE, g_cb3 + 62, g_bng + 62, g_bnb + 62, sbuf, 14, 8);
    for (int idx = tid; idx < 496 * 4; idx += 256) {
        int p = idx >> 2, g = idx & 3; int n = p >> 3, c = p & 7;
        sbuf[(n * 14 + c) * 4 + g] = sx2[idx];
    }
    __syncthreads();
    conv_g<3>(tid, sbuf, 14, 12, cw3T + 2 * CW3T_ONE, g_cb3 + 124, g_bng + 124, g_bnb + 124, sxx1, 30, 0);

    conv_g<5>(tid, sx2, 8, 4, cw5T, g_cb5, g_bng + 186, g_bnb + 186, sbuf, 12, 0);
    for (int idx = tid; idx < 496 * 4; idx += 256) {
        int p = idx >> 2, g = idx & 3; int n = p >> 3, c = p & 7;
        sbuf[(n * 12 + 4 + c) * 4 + g] = sx2[idx];
    }
    __syncthreads();
    conv_g<5>(tid, sbuf, 12, 8, cw5T + CW5T_ONE, g_cb5 + 62, g_bng + 248, g_bnb + 248, sxx1, 30, 12);

    conv_g<3>(tid, sx2, 8, 6, cw3T + 3 * CW3T_ONE, g_cb3 + 186, g_bng + 310, g_bnb + 310, sbuf, 14, 0);
    for (int idx = tid; idx < 496 * 4; idx += 256) {
        int p = idx >> 2, g = idx & 3; int n = p >> 3, c = p & 7;
        sbuf[(n * 14 + 6 + c) * 4 + g] = sx2[idx];
    }
    __syncthreads();
    conv_g<5>(tid, sbuf, 14, 10, cw5T + 2 * CW5T_ONE, g_cb5 + 124, g_bng + 372, g_bnb + 372, sxx1, 30, 20);

    chan_att_g(tid, sxx1, 30, g_caw1 + 930, g_caw2 + 930, spool, shid);

    for (int idx = tid; idx < 1860 * 4; idx += 256) {
        int p = idx >> 2, g = idx & 3;
        g_xx1[(size_t)(grp * 4 + g) * 1860 + p] = sxx1[idx];
    }
}

// ================= transformer =================
// QKV GEMM (R11-proven): 16 samples/block, LN1 fused, 2 outputs/thread
__global__ __launch_bounds__(256) void k_qkv()
{
    __shared__ __align__(16) float sxf[310 * 16];
    const int tid = threadIdx.x;
    const int grp = blockIdx.x / 7;
    const int tile = blockIdx.x - grp * 7;

    for (int idx = tid; idx < 310 * 16; idx += 256) {
        int f = idx >> 4, g = idx & 15;
        sxf[idx] = g_xin[(size_t)(grp * 16 + g) * 310 + f];
    }
    __syncthreads();
    // LN1 in place
    for (int it = tid; it < 992; it += 256) {
        int i = it >> 4, g = it & 15;
        float xv[5], m = 0.f, s = 0.f;
        #pragma unroll
        for (int c = 0; c < 5; ++c) { xv[c] = sxf[(i * 5 + c) * 16 + g]; m += xv[c]; s += xv[c] * xv[c]; }
        m *= 0.2f;
        float inv = rsqrtf(fmaxf(s * 0.2f - m * m, 0.f) + 1e-5f);
        #pragma unroll
        for (int c = 0; c < 5; ++c)
            sxf[(i * 5 + c) * 16 + g] = (xv[c] - m) * inv * g_ln1g[c] + g_ln1bb[c];
    }
    __syncthreads();

    int o0 = tile * 512 + tid;
    if (o0 >= 3348) return;
    int o1 = o0 + 256;
    const int valid1 = (o1 < 3348);
    int o1c = valid1 ? o1 : 3347;   // clamp: reads valid memory, result discarded

    float bias0 = (o0 < 744) ? g_qb[o0] : (o0 < 1488) ? g_kb[o0 - 744] : g_vb[o0 - 1488];
    float bias1 = (o1c < 744) ? g_qb[o1c] : (o1c < 1488) ? g_kb[o1c - 744] : g_vb[o1c - 1488];
    const float* W0 = g_qkvT + (size_t)o0 * 312;
    const float* W1 = g_qkvT + (size_t)o1c * 312;

    float accA[16], accB[16];
    #pragma unroll
    for (int g = 0; g < 16; ++g) { accA[g] = bias0; accB[g] = bias1; }

#define QS2(wka, wkb, ff) { \
    const float4* xp = (const float4*)(sxf + (ff) * 16); \
    const float4 x0 = xp[0], x1 = xp[1], x2 = xp[2], x3 = xp[3]; \
    float xs[16]; \
    *(float4*)(xs) = x0; *(float4*)(xs + 4) = x1; *(float4*)(xs + 8) = x2; *(float4*)(xs + 12) = x3; \
    _Pragma("unroll") \
    for (int g = 0; g < 16; ++g) { accA[g] += (wka) * xs[g]; accB[g] += (wkb) * xs[g]; } }

    for (int f = 0; f < 308; f += 4) {
        const float4 wa = *(const float4*)(W0 + f);
        const float4 wb = *(const float4*)(W1 + f);
        QS2(wa.x, wb.x, f) QS2(wa.y, wb.y, f + 1) QS2(wa.z, wb.z, f + 2) QS2(wa.w, wb.w, f + 3)
    }
    QS2(W0[308], W1[308], 308) QS2(W0[309], W1[309], 309)
#undef QS2

    #pragma unroll
    for (int g = 0; g < 16; ++g) {
        size_t base = (size_t)(grp * 16 + g) * 3348;
        g_qkv[base + o0] = accA[g];
        if (valid1) g_qkv[base + o1] = accB[g];
    }
}

// per-sample attention -> g_x2t
// R15 fused QK^T+row-max; R16: rcp merged into v-fold (one fewer pass+barrier/head)
__global__ __launch_bounds__(256) void k_attn()
{
    __shared__ float sqkv[3348];
    __shared__ float satt[3844];
    __shared__ float sred[496];
    const int tid = threadIdx.x;
    const int b = blockIdx.x;

    for (int i = tid; i < 3348; i += 256) sqkv[i] = g_qkv[(size_t)b * 3348 + i];
    __syncthreads();

    for (int h = 0; h < 6; ++h) {
        const float* q = sqkv + h * 124;
        const float* k = sqkv + 744 + h * 124;
        float* v = sqkv + 1488 + h * 310;
        // fused QK^T + row-max partials: thread = (j-strip qq, row i)
        if (tid < 248) {
            int qq = tid / 62, i = tid - qq * 62;
            int j0 = qq * 16, j1 = j0 + 16 > 62 ? 62 : j0 + 16;
            float qa = q[i * 2], qb2 = q[i * 2 + 1];
            float* row = satt + i * 62;
            float mx = -3.4e38f;
            for (int j = j0; j < j1; ++j) {
                float s = (qa * k[j * 2] + qb2 * k[j * 2 + 1]) * INV_SQRT2;
                row[j] = s;
                mx = fmaxf(mx, s);
            }
            sred[qq * 62 + i] = mx;
        }
        __syncthreads();
        // exp + row-sum partials
        if (tid < 248) {
            int qq = tid / 62, i = tid - qq * 62;
            int j0 = qq * 16, j1 = j0 + 16 > 62 ? 62 : j0 + 16;
            float rmx = fmaxf(fmaxf(sred[i], sred[62 + i]), fmaxf(sred[124 + i], sred[186 + i]));
            float* row = satt + i * 62;
            float s = 0.f;
            for (int j = j0; j < j1; ++j) { float e = expf(row[j] - rmx); row[j] = e; s += e; }
            sred[248 + qq * 62 + i] = s;
        }
        __syncthreads();
        // fold 1/rowsum into v rows (rcp fused; R6-proven form)
        for (int t = tid; t < 310; t += 256) {
            int j = t / 5;
            float inv = 1.f / (sred[248 + j] + sred[310 + j] + sred[372 + j] + sred[434 + j]);
            v[t] *= inv;
        }
        __syncthreads();
        for (int idx = tid; idx < 310; idx += 256) {
            int i = idx / 5, c = idx - i * 5;
            float acc = 0.f;
            for (int j = 0; j < 62; ++j) acc += satt[j * 62 + i] * v[j * 5 + c];
            g_x2t[(size_t)b * 1860 + i * 30 + h * 5 + c] = acc;
        }
        __syncthreads();
    }
}

// lin1 + residual + LN2 + FFN + residual
// R16: lin1 partials in THIRDS (930 items x 620-f): worst-thread path -11%
__global__ __launch_bounds__(256) void k_lin1ffn()
{
    __shared__ __align__(16) float sx2t[1860 * 4];
    __shared__ __align__(16) float sX[310 * 4];
    __shared__ __align__(16) float sx21[310 * 4];
    __shared__ __align__(16) float sxf[310 * 4];
    __shared__ __align__(16) float shg[186 * 4];
    __shared__ __align__(16) float spart[930 * 4];
    const int tid = threadIdx.x;
    const int grp = blockIdx.x;

    for (int idx = tid; idx < 1860 * 4; idx += 256) {
        int f = idx >> 2, g = idx & 3;
        sx2t[idx] = g_x2t[(size_t)(grp * 4 + g) * 1860 + f];
    }
    for (int idx = tid; idx < 310 * 4; idx += 256) {
        int o = idx >> 2, g = idx & 3;
        sX[idx] = g_xin[(size_t)(grp * 4 + g) * 310 + o];
    }
    __syncthreads();

#define XSTEP(wk, ff, Xb) { const float4 xv = *(const float4*)((Xb) + (ff) * 4); \
                            a0 += (wk) * xv.x; a1 += (wk) * xv.y; a2 += (wk) * xv.z; a3 += (wk) * xv.w; }
    // lin1 partials: thirds f in [0,620) [620,1240) [1240,1860), all 16B-aligned
    for (int item = tid; item < 930; item += 256) {
        int t = item / 310, o = item - t * 310;
        const float* W = g_lin1T + (size_t)o * 1860 + t * 620;
        const float* Xb = sx2t + t * 620 * 4;
        float a0 = 0.f, a1 = 0.f, a2 = 0.f, a3 = 0.f;
        for (int f = 0; f < 620; f += 4) {
            const float4 w = *(const float4*)(W + f);
            XSTEP(w.x, f, Xb) XSTEP(w.y, f + 1, Xb) XSTEP(w.z, f + 2, Xb) XSTEP(w.w, f + 3, Xb)
        }
        spart[item * 4 + 0] = a0; spart[item * 4 + 1] = a1;
        spart[item * 4 + 2] = a2; spart[item * 4 + 3] = a3;
    }
    __syncthreads();
    for (int o = tid; o < 310; o += 256) {
        float bias = g_lin1b[o];
        for (int g = 0; g < 4; ++g)
            sx21[o * 4 + g] = spart[o * 4 + g] + spart[(310 + o) * 4 + g] + spart[(620 + o) * 4 + g]
                            + bias + sX[o * 4 + g];
    }
    __syncthreads();

    if (tid < 248) {
        int i = tid >> 2, g = tid & 3;
        float m = 0.f, s = 0.f;
        for (int c = 0; c < 5; ++c) { float v = sx21[(i * 5 + c) * 4 + g]; m += v; s += v * v; }
        m *= 0.2f;
        float inv = rsqrtf(fmaxf(s * 0.2f - m * m, 0.f) + 1e-5f);
        for (int c = 0; c < 5; ++c)
            sxf[(i * 5 + c) * 4 + g] = (sx21[(i * 5 + c) * 4 + g] - m) * inv * g_ln2g[c] + g_ln2bb[c];
    }
    __syncthreads();

    if (tid < 186) {
        const float* W = g_ffn1T + (size_t)tid * 312;
        float bias = g_ffnb1[tid];
        float a0 = bias, a1 = bias, a2 = bias, a3 = bias;
        for (int f = 0; f < 308; f += 4) {
            const float4 w = *(const float4*)(W + f);
            XSTEP(w.x, f, sxf) XSTEP(w.y, f + 1, sxf) XSTEP(w.z, f + 2, sxf) XSTEP(w.w, f + 3, sxf)
        }
        XSTEP(W[308], 308, sxf) XSTEP(W[309], 309, sxf)
        shg[tid * 4 + 0] = 0.5f * a0 * (1.f + erff(a0 * INV_SQRT2));
        shg[tid * 4 + 1] = 0.5f * a1 * (1.f + erff(a1 * INV_SQRT2));
        shg[tid * 4 + 2] = 0.5f * a2 * (1.f + erff(a2 * INV_SQRT2));
        shg[tid * 4 + 3] = 0.5f * a3 * (1.f + erff(a3 * INV_SQRT2));
    }
    __syncthreads();

    for (int o = tid; o < 310; o += 256) {
        const float* W = g_ffn2T + (size_t)o * 188;
        float bias = g_ffnb2[o];
        float a0 = bias, a1 = bias, a2 = bias, a3 = bias;
        for (int j = 0; j < 184; j += 4) {
            const float4 w = *(const float4*)(W + j);
            XSTEP(w.x, j, shg) XSTEP(w.y, j + 1, shg) XSTEP(w.z, j + 2, shg) XSTEP(w.w, j + 3, shg)
        }
        XSTEP(W[184], 184, shg) XSTEP(W[185], 185, shg)
        g_xt[(size_t)(grp * 4 + 0) * 310 + o] = a0 + sx21[o * 4 + 0];
        g_xt[(size_t)(grp * 4 + 1) * 310 + o] = a1 + sx21[o * 4 + 1];
        g_xt[(size_t)(grp * 4 + 2) * 310 + o] = a2 + sx21[o * 4 + 2];
        g_xt[(size_t)(grp * 4 + 3) * 310 + o] = a3 + sx21[o * 4 + 3];
    }
#undef XSTEP
}

// ================= GAT (R9-proven: fold passes + register layer-2 accum) =================
__global__ __launch_bounds__(256) void k_gat(void* __restrict__ out, int B)
{
    __shared__ __align__(16) float satt[3844];
    __shared__ __align__(16) float sh[1984];
    __shared__ __align__(16) float sbufA[2170];   // layer1: f32 sxx; layer2: soutg
    __shared__ float ssrc[124];
    __shared__ float sred[496];
    __shared__ float sacc2[620];
    const int tid = threadIdx.x;
    const int b = blockIdx.x;
    const int isbf = g_flag;
    float* sxx = sbufA;

    for (int idx = tid; idx < 2170; idx += 256) {
        int n = idx / 35, f = idx - n * 35;
        sxx[idx] = (f < 30) ? g_xx1[(size_t)b * 1860 + n * 30 + f]
                            : g_xt[(size_t)b * 310 + n * 5 + (f - 30)];
    }

    float racc0[10], racc1[10];
    #pragma unroll
    for (int o = 0; o < 10; ++o) { racc0[o] = 0.f; racc1[o] = 0.f; }

    for (int h = 0; h < 4; ++h) {
        for (int idx = tid; idx < 1120; idx += 256) satt[idx] = g_gatW[h * 1120 + idx];
        __syncthreads();
        float* sp1 = satt + 1200;
        float* sp2 = satt + 1800;
        for (int item = tid; item < 496; item += 256) {
            int n = item >> 3, oqi = item & 7, oq = oqi * 4;
            const float* xr = sxx + n * 35;
            float a0 = 0.f, a1 = 0.f, a2 = 0.f, a3 = 0.f;
            for (int f = 0; f < 35; ++f) {
                float xv = xr[f];
                const float4 w = *(const float4*)(satt + f * 32 + oq);
                a0 += xv * w.x; a1 += xv * w.y; a2 += xv * w.z; a3 += xv * w.w;
            }
            float4 r; r.x = a0; r.y = a1; r.z = a2; r.w = a3;
            *(float4*)(sh + n * 32 + oq) = r;
            float l0 = a0 > 0.f ? a0 : 0.2f * a0;
            float l1 = a1 > 0.f ? a1 : 0.2f * a1;
            float l2 = a2 > 0.f ? a2 : 0.2f * a2;
            float l3 = a3 > 0.f ? a3 : 0.2f * a3;
            const float* ga = g_gata + h * 64 + oq;
            sp1[n * 9 + oqi] = l0 * ga[0] + l1 * ga[1] + l2 * ga[2] + l3 * ga[3];
            sp2[n * 9 + oqi] = l0 * ga[32] + l1 * ga[33] + l2 * ga[34] + l3 * ga[35];
        }
        __syncthreads();
        if (tid < 124) {
            int which = tid >= 62; int n = tid - which * 62;
            const float* pp = which ? sp2 : sp1;
            float s = 0.f;
            for (int q = 0; q < 8; ++q) s += pp[n * 9 + q];
            ssrc[tid] = s;
        }
        __syncthreads();
        if (tid < 248) {
            int q = tid / 62, m = tid - q * 62;
            int n0 = q * 16, n1 = n0 + 16 > 62 ? 62 : n0 + 16;
            float s2m = ssrc[62 + m];
            float mx = -3.4e38f;
            for (int n = n0; n < n1; ++n) {
                float dj = 0.8f * g_L[n * 62 + m] + 0.2f * (ssrc[n] + s2m);
                dj = dj > 0.f ? dj : -1e12f;
                satt[n * 62 + m] = dj;
                mx = fmaxf(mx, dj);
            }
            sred[q * 62 + m] = mx;
        }
        __syncthreads();
        if (tid < 248) {
            int q = tid / 62, m = tid - q * 62;
            int n0 = q * 16, n1 = n0 + 16 > 62 ? 62 : n0 + 16;
            float cmx = fmaxf(fmaxf(sred[m], sred[62 + m]), fmaxf(sred[124 + m], sred[186 + m]));
            float s = 0.f;
            for (int n = n0; n < n1; ++n) {
                float e = expf(satt[n * 62 + m] - cmx);
                satt[n * 62 + m] = e;
                s += e;
            }
            sred[248 + q * 62 + m] = s;
        }
        __syncthreads();
        if (tid < 62)
            ssrc[tid] = 1.f / (sred[248 + tid] + sred[310 + tid] + sred[372 + tid] + sred[434 + tid]);
        __syncthreads();
        for (int item = tid; item < 1984; item += 256) sh[item] *= ssrc[item >> 5];
        __syncthreads();
        if (tid < 248) {
            int ip = tid >> 3, oqi = tid & 7, oq = oqi * 4;
            int i0 = ip * 2;
            const float* ar0 = satt + i0 * 62;
            const float* ar1 = ar0 + 62;
            float a00 = 0.f, a01 = 0.f, a02 = 0.f, a03 = 0.f;
            float a10 = 0.f, a11 = 0.f, a12 = 0.f, a13 = 0.f;
            for (int j = 0; j < 62; ++j) {
                const float4 hv = *(const float4*)(sh + j * 32 + oq);
                float v0 = ar0[j], v1 = ar1[j];
                a00 += v0 * hv.x; a01 += v0 * hv.y; a02 += v0 * hv.z; a03 += v0 * hv.w;
                a10 += v1 * hv.x; a11 += v1 * hv.y; a12 += v1 * hv.z; a13 += v1 * hv.w;
            }
            a00 = fmaxf(a00, 0.f); a01 = fmaxf(a01, 0.f); a02 = fmaxf(a02, 0.f); a03 = fmaxf(a03, 0.f);
            a10 = fmaxf(a10, 0.f); a11 = fmaxf(a11, 0.f); a12 = fmaxf(a12, 0.f); a13 = fmaxf(a13, 0.f);
            const float* W2 = g_outW + (h * 32 + oq) * 10;
            #pragma unroll
            for (int o = 0; o < 10; ++o) {
                float w0 = W2[o], w1 = W2[10 + o], w2c = W2[20 + o], w3 = W2[30 + o];
                racc0[o] += a00 * w0 + a01 * w1 + a02 * w2c + a03 * w3;
                racc1[o] += a10 * w0 + a11 * w1 + a12 * w2c + a13 * w3;
            }
        }
        __syncthreads();
    }

    if (tid < 248) {
        float* dst = satt + tid * 20;
        #pragma unroll
        for (int o = 0; o < 10; ++o) { dst[o] = racc0[o]; dst[10 + o] = racc1[o]; }
    }
    __syncthreads();
    for (int idx = tid; idx < 620; idx += 256) {
        int i = idx / 10, o = idx - i * 10;
        int ip = i >> 1, half = i & 1;
        const float* src = satt + (ip * 8) * 20 + half * 10 + o;
        float s = 0.f;
        #pragma unroll
        for (int q = 0; q < 8; ++q) s += src[q * 20];
        sacc2[idx] = s;
    }
    __syncthreads();

    float* sh2   = sacc2;
    float* soutg = sbufA;

    if (tid < 124) {
        int which = tid >= 62; int n = tid - which * 62;
        float acc = 0.f;
        for (int o = 0; o < 10; ++o) {
            float v = sh2[n * 10 + o]; v = v > 0.f ? v : 0.2f * v;
            acc += v * g_outa[which * 10 + o];
        }
        ssrc[tid] = acc;
    }
    __syncthreads();
    if (tid < 248) {
        int q = tid / 62, m = tid - q * 62;
        int n0 = q * 16, n1 = n0 + 16 > 62 ? 62 : n0 + 16;
        float s2m = ssrc[62 + m];
        float mx = -3.4e38f;
        for (int n = n0; n < n1; ++n) {
            float dj = 0.8f * g_L[n * 62 + m] + 0.2f * (ssrc[n] + s2m);
            dj = dj > 0.f ? dj : -1e12f;
            satt[n * 62 + m] = dj;
            mx = fmaxf(mx, dj);
        }
        sred[q * 62 + m] = mx;
    }
    __syncthreads();
    if (tid < 248) {
        int q = tid / 62, m = tid - q * 62;
        int n0 = q * 16, n1 = n0 + 16 > 62 ? 62 : n0 + 16;
        float cmx = fmaxf(fmaxf(sred[m], sred[62 + m]), fmaxf(sred[124 + m], sred[186 + m]));
        float s = 0.f;
        for (int n = n0; n < n1; ++n) {
            float e = expf(satt[n * 62 + m] - cmx);
            satt[n * 62 + m] = e;
            s += e;
        }
        sred[248 + q * 62 + m] = s;
    }
    __syncthreads();
    if (tid < 62)
        ssrc[tid] = 1.f / (sred[248 + tid] + sred[310 + tid] + sred[372 + tid] + sred[434 + tid]);
    __syncthreads();
    for (int item = tid; item < 620; item += 256) sh2[item] *= ssrc[item / 10];
    __syncthreads();
    for (int idx = tid; idx < 620; idx += 256) {
        int i = idx / 10, o = idx - i * 10;
        const float* ar = satt + i * 62;
        float acc = 0.f;
        for (int j = 0; j < 62; ++j) acc += ar[j] * sh2[j * 10 + o];
        soutg[idx] = fmaxf(acc, 0.f);
    }
    __syncthreads();

    if (tid < 62) {
        const float* r = soutg + tid * 10;
        float e[10]; float mx = -3.4e38f;
        for (int o = 0; o < 10; ++o) { float v = r[o]; v = v > 0.f ? v : expm1f(v); e[o] = v; mx = fmaxf(mx, v); }
        float sum = 0.f;
        for (int o = 0; o < 10; ++o) sum += expf(e[o] - mx);
        float ls = logf(sum) + mx;
        for (int o = 0; o < 10; ++o) {
            float v = e[o] - ls;
            size_t off = (size_t)b * 620 + tid * 10 + o;
            if (isbf) ((bf16*)out)[off] = f2b(v); else ((float*)out)[off] = v;
            g_x11f[off] = v;
        }
    }
}

// fc1->fc2->fc3 tail, 8 samples/block (R6-proven)
__global__ __launch_bounds__(256) void k_fc(void* __restrict__ out, int B)
{
    __shared__ __align__(16) float sxf[620 * 8];
    __shared__ __align__(16) float st1[256 * 8];
    __shared__ __align__(16) float st2[32 * 8];
    const int tid = threadIdx.x;
    const int grp = blockIdx.x;
    const int isbf = g_flag;

    for (int idx = tid; idx < 620 * 8; idx += 256) {
        int f = idx >> 3, g = idx & 7;
        sxf[idx] = g_x11f[(size_t)(grp * 8 + g) * 620 + f];
    }
    __syncthreads();

    {
        const float* W = g_fc1T + (size_t)tid * 620;
        float bias = g_fc1b[tid];
        float a0 = bias, a1 = bias, a2 = bias, a3 = bias, a4 = bias, a5 = bias, a6 = bias, a7 = bias;
#define FSTEP(wk, ff) { const float4 p = *(const float4*)(sxf + (ff) * 8); \
                        const float4 qq = *(const float4*)(sxf + (ff) * 8 + 4); \
                        a0 += (wk) * p.x; a1 += (wk) * p.y; a2 += (wk) * p.z; a3 += (wk) * p.w; \
                        a4 += (wk) * qq.x; a5 += (wk) * qq.y; a6 += (wk) * qq.z; a7 += (wk) * qq.w; }
        for (int f = 0; f < 620; f += 4) {
            const float4 w = *(const float4*)(W + f);
            FSTEP(w.x, f) FSTEP(w.y, f + 1) FSTEP(w.z, f + 2) FSTEP(w.w, f + 3)
        }
#undef FSTEP
        float4 r0; r0.x = a0; r0.y = a1; r0.z = a2; r0.w = a3;
        float4 r1; r1.x = a4; r1.y = a5; r1.z = a6; r1.w = a7;
        *(float4*)(st1 + tid * 8)     = r0;
        *(float4*)(st1 + tid * 8 + 4) = r1;
    }
    __syncthreads();
    {
        int g = tid >> 5, o = tid & 31;
        float acc = g_fc2b[o];
        for (int f = 0; f < 256; ++f) acc += st1[f * 8 + g] * g_fc2w[f * 32 + o];
        st2[o * 8 + g] = acc;
    }
    __syncthreads();
    if (tid < 32) {
        int g = tid >> 2, o = tid & 3;
        float acc = g_fc3b[o];
        for (int f = 0; f < 32; ++f) acc += st2[f * 8 + g] * g_fc3w[f * 4 + o];
        size_t off = (size_t)B * 620 + (size_t)(grp * 8 + g) * 4 + o;
        if (isbf) ((bf16*)out)[off] = f2b(acc); else ((float*)out)[off] = acc;
    }
}

extern "C" void kernel_launch(void* const* d_in, const int* in_sizes, int n_in,
                              void* d_out, int out_size, void* d_ws, size_t ws_size,
                              hipStream_t stream)
{
    const int B = in_sizes[0] / 310;   // 2048
    const int wprep_blocks = (WPREP_TOTAL + 255) / 256;

    k_probe<<<1, 256, 0, stream>>>(d_in[0]);

    k_wprep<<<wprep_blocks, 256, 0, stream>>>(
        d_in[10], d_in[12], d_in[14], d_in[16], d_in[22], d_in[24], d_in[30],
        d_in[26], d_in[28], d_in[0], d_in[2], d_in[4]);
    k_prep<<<72, 256, 0, stream>>>(
        d_in[1], d_in[3], d_in[5], d_in[6], d_in[7], d_in[8], d_in[9],
        d_in[11], d_in[13], d_in[15], d_in[17], d_in[18], d_in[19], d_in[20], d_in[21],
        d_in[23], d_in[25], d_in[27], d_in[29],
        d_in[31], d_in[32], d_in[33], d_in[34], d_in[35]);

    k_conv<<<B / 4, 256, 0, stream>>>();
    k_qkv<<<(B / 16) * 7, 256, 0, stream>>>();
    k_attn<<<B, 256, 0, stream>>>();
    k_lin1ffn<<<B / 4, 256, 0, stream>>>();
    k_gat<<<B, 256, 0, stream>>>(d_out, B);
    k_fc<<<B / 8, 256, 0, stream>>>(d_out, B);
}

// Round 17
// 784.385 us; speedup vs baseline: 1.1912x; 1.1371x over previous
//
#include <hip/hip_runtime.h>
#include <hip/hip_bf16.h>

typedef __hip_bfloat16 bf16;

__device__ __forceinline__ float b2f(bf16 v) { return __bfloat162float(v); }
__device__ __forceinline__ bf16  f2b(float v) { return __float2bfloat16(v); }

__device__ __forceinline__ float ldany(int isbf, const void* p, int i)
{
    return isbf ? b2f(((const bf16*)p)[i]) : ((const float*)p)[i];
}

#define SELU_SCALE 1.0507009873554805f
#define SELU_ALPHA 1.6732632423543772f
#define INV_SQRT2  0.7071067811865475f
#define SELU_F(v) ((v) > 0.f ? SELU_SCALE * (v) : SELU_SCALE * SELU_ALPHA * expm1f(v))

#define NB 2048   // batch (fixed by reference)

// dtype flag + global staging
__device__ int   g_flag;                        // 1 = bf16 tensors, 0 = f32
__device__ float g_xin [(size_t)NB * 310];      // f32 copy of x
__device__ float g_qkv [(size_t)NB * 3348];     // q(744)|k(744)|v(1860) per sample
__device__ float g_x2t [(size_t)NB * 1860];     // attention output (pre-lin1)
__device__ float g_xx1 [(size_t)NB * 1860];     // conv-branch output
__device__ float g_xt  [(size_t)NB * 310];      // transformer output
__device__ float g_x11f[(size_t)NB * 620];      // f32 copy of x11 for k_fc
__device__ float g_L   [3844];                  // normalized Laplacian

// transposed (contraction-contiguous) f32 weights; row strides padded to 16B
__device__ float g_qkvT [(size_t)3348 * 312];   // [o][f] f<310 valid
__device__ float g_lin1T[(size_t)310 * 1860];   // [o][f]
__device__ float g_ffn1T[(size_t)186 * 312];    // [j][f] f<310 valid
__device__ float g_ffn2T[(size_t)310 * 188];    // [o][j] j<186 valid
__device__ float g_fc1T [(size_t)256 * 620];    // [o][f]
__device__ __align__(16) float g_gatW[4480];    // [h][f][o] f32 copy of gat_w
__device__ __align__(16) float g_outW[1280];    // [f][o]    f32 copy of out_w
// conv weights transposed to [(i*K+k)][o] with o padded to 64 (o>=62 -> 0)
#define CW3T_ONE (62 * 3 * 64)                  // 11904
#define CW5T_ONE (62 * 5 * 64)                  // 19840
#define CW3T_SZ  (4 * CW3T_ONE)                 // 47616
#define CW5T_SZ  (3 * CW5T_ONE)                 // 59520
__device__ __align__(16) float g_cwT[CW3T_SZ + CW5T_SZ];

// f32 staged small params
__device__ float g_cb3[248], g_cb5[186], g_bng[434], g_bnb[434];
__device__ float g_caw1[1860], g_caw2[1860];
__device__ float g_qb[744], g_kb[744], g_vb[1860];
__device__ float g_lin1b[310], g_ln1g[5], g_ln1bb[5], g_ln2g[5], g_ln2bb[5];
__device__ float g_ffnb1[186], g_ffnb2[310];
__device__ float g_gata[256], g_outa[20];
__device__ float g_fc1b[256], g_fc2w[8192], g_fc2b[32], g_fc3w[128], g_fc3b[4];

// ---- dtype probe ----
__global__ void k_probe(const void* x0)
{
    __shared__ int cnt;
    if (threadIdx.x == 0) cnt = 0;
    __syncthreads();
    const bf16* p = (const bf16*)x0;
    int bad = 0;
    for (int i = threadIdx.x; i < 4096; i += 256) {
        float v = b2f(p[i]);
        if (!(fabsf(v) < 1e6f)) bad++;
    }
    atomicAdd(&cnt, bad);
    __syncthreads();
    if (threadIdx.x == 0) g_flag = (cnt < 32) ? 1 : 0;
}

// ---- one-time big-array transposes / conversions (runtime dtype branch) ----
#define QKVT_SZ  (3348 * 312)
#define LIN1T_SZ (310 * 1860)
#define FFN1T_SZ (186 * 312)
#define FFN2T_SZ (310 * 188)
#define FC1T_SZ  (256 * 620)
#define GATW_SZ  4480
#define OUTW_SZ  1280
#define XIN_SZ   (NB * 310)
#define WPREP_TOTAL (QKVT_SZ + LIN1T_SZ + FFN1T_SZ + FFN2T_SZ + FC1T_SZ + GATW_SZ + OUTW_SZ + XIN_SZ + CW3T_SZ + CW5T_SZ)

__global__ __launch_bounds__(256) void k_wprep(
    const void* __restrict__ qw, const void* __restrict__ kw, const void* __restrict__ vw,
    const void* __restrict__ lin1_w, const void* __restrict__ ffn_w1, const void* __restrict__ ffn_w2,
    const void* __restrict__ fc1_w, const void* __restrict__ gat_w, const void* __restrict__ out_w,
    const void* __restrict__ x, const void* __restrict__ cw3, const void* __restrict__ cw5)
{
    const int isbf = g_flag;
    int idx = blockIdx.x * 256 + threadIdx.x;
    if (idx >= WPREP_TOTAL) return;
    if (idx < QKVT_SZ) {
        int o = idx / 312, f = idx - o * 312;
        float v = 0.f;
        if (f < 310) {
            if (o < 744)       { int h = o / 124, c = o - h * 124; v = ldany(isbf, qw, h * 38440 + f * 124 + c); }
            else if (o < 1488) { int r = o - 744;  int h = r / 124, c = r - h * 124; v = ldany(isbf, kw, h * 38440 + f * 124 + c); }
            else               { int r = o - 1488; int h = r / 310, c = r - h * 310; v = ldany(isbf, vw, h * 96100 + f * 310 + c); }
        }
        g_qkvT[idx] = v;
        return;
    }
    idx -= QKVT_SZ;
    if (idx < LIN1T_SZ) {
        int o = idx / 1860, f = idx - o * 1860;
        g_lin1T[idx] = ldany(isbf, lin1_w, f * 310 + o);
        return;
    }
    idx -= LIN1T_SZ;
    if (idx < FFN1T_SZ) {
        int j = idx / 312, f = idx - j * 312;
        g_ffn1T[idx] = (f < 310) ? ldany(isbf, ffn_w1, f * 186 + j) : 0.f;
        return;
    }
    idx -= FFN1T_SZ;
    if (idx < FFN2T_SZ) {
        int o = idx / 188, j = idx - o * 188;
        g_ffn2T[idx] = (j < 186) ? ldany(isbf, ffn_w2, j * 310 + o) : 0.f;
        return;
    }
    idx -= FFN2T_SZ;
    if (idx < FC1T_SZ) {
        int o = idx / 620, f = idx - o * 620;
        g_fc1T[idx] = ldany(isbf, fc1_w, f * 256 + o);
        return;
    }
    idx -= FC1T_SZ;
    if (idx < GATW_SZ) { g_gatW[idx] = ldany(isbf, gat_w, idx); return; }
    idx -= GATW_SZ;
    if (idx < OUTW_SZ) { g_outW[idx] = ldany(isbf, out_w, idx); return; }
    idx -= OUTW_SZ;
    if (idx < XIN_SZ) { g_xin[idx] = ldany(isbf, x, idx); return; }
    idx -= XIN_SZ;
    if (idx < CW3T_SZ) {
        int c = idx / CW3T_ONE, r = idx - c * CW3T_ONE;
        int ik = r >> 6, o = r & 63;
        g_cwT[idx] = (o < 62) ? ldany(isbf, cw3, c * 11532 + o * 186 + ik) : 0.f;
        return;
    }
    idx -= CW3T_SZ;
    {
        int c = idx / CW5T_ONE, r = idx - c * CW5T_ONE;
        int ik = r >> 6, o = r & 63;
        g_cwT[CW3T_SZ + idx] = (o < 62) ? ldany(isbf, cw5, c * 19220 + o * 310 + ik) : 0.f;
    }
}

// ---- Laplacian + all small-param conversions (runtime dtype branch) ----
__global__ __launch_bounds__(256) void k_prep(
    const void* __restrict__ A,
    const void* __restrict__ cb3, const void* __restrict__ cb5,
    const void* __restrict__ bn_g, const void* __restrict__ bn_b,
    const void* __restrict__ ca_w1, const void* __restrict__ ca_w2,
    const void* __restrict__ qb, const void* __restrict__ kb, const void* __restrict__ vb,
    const void* __restrict__ lin1_b,
    const void* __restrict__ ln1_g, const void* __restrict__ ln1_b,
    const void* __restrict__ ln2_g, const void* __restrict__ ln2_b,
    const void* __restrict__ ffn_b1, const void* __restrict__ ffn_b2,
    const void* __restrict__ gat_a, const void* __restrict__ out_a,
    const void* __restrict__ fc1_b, const void* __restrict__ fc2_w, const void* __restrict__ fc2_b,
    const void* __restrict__ fc3_w, const void* __restrict__ fc3_b)
{
    const int isbf = g_flag;
    __shared__ float sdinv[62];
    const int tid = threadIdx.x;
    if (blockIdx.x == 0) {
        if (tid < 62) {
            float s = 0.f;
            for (int m = 0; m < 62; ++m) s += fmaxf(ldany(isbf, A, tid * 62 + m), 0.f);
            sdinv[tid] = rsqrtf(s + 1e-10f);
        }
        __syncthreads();
        for (int idx = tid; idx < 3844; idx += 256) {
            int n = idx / 62, m = idx - n * 62;
            g_L[idx] = sdinv[n] * fmaxf(ldany(isbf, A, idx), 0.f) * sdinv[m];
        }
        return;
    }
    int idx = (blockIdx.x - 1) * 256 + tid;
#define CP(dst, src, n) { if (idx < (n)) { dst[idx] = ldany(isbf, src, idx); return; } idx -= (n); }
    CP(g_cb3, cb3, 248) CP(g_cb5, cb5, 186)
    CP(g_bng, bn_g, 434) CP(g_bnb, bn_b, 434)
    CP(g_caw1, ca_w1, 1860) CP(g_caw2, ca_w2, 1860)
    CP(g_qb, qb, 744) CP(g_kb, kb, 744) CP(g_vb, vb, 1860)
    CP(g_lin1b, lin1_b, 310)
    CP(g_ln1g, ln1_g, 5) CP(g_ln1bb, ln1_b, 5) CP(g_ln2g, ln2_g, 5) CP(g_ln2bb, ln2_b, 5)
    CP(g_ffnb1, ffn_b1, 186) CP(g_ffnb2, ffn_b2, 310)
    CP(g_gata, gat_a, 256) CP(g_outa, out_a, 20)
    CP(g_fc1b, fc1_b, 256) CP(g_fc2w, fc2_w, 8192) CP(g_fc2b, fc2_b, 32)
    CP(g_fc3w, fc3_w, 128) CP(g_fc3b, fc3_b, 4)
#undef CP
}

// ================= conv helpers (R10-proven) =================
template<int K>
__device__ void conv_g(int tid, const float* sIn, int Lin, int Lout,
                       const float* __restrict__ WT,
                       const float* __restrict__ cb, const float* __restrict__ bng,
                       const float* __restrict__ bnb,
                       float* sOut, int ostride, int ooff)
{
    const float bninv = rsqrtf(1.0f + 1e-5f);
    if (tid < 16 * Lout) {
        int oq = tid / Lout, l = tid - oq * Lout;
        const float* wp = WT + oq * 4;
        float4 c0 = {0,0,0,0}, c1 = {0,0,0,0}, c2 = {0,0,0,0}, c3 = {0,0,0,0};
        #pragma unroll 2
        for (int i = 0; i < 62; ++i) {
            #pragma unroll
            for (int k = 0; k < K; ++k) {
                const float4 w  = *(const float4*)(wp + (i * K + k) * 64);
                const float4 xv = *(const float4*)(sIn + (i * Lin + l + k) * 4);
                c0.x += w.x * xv.x; c0.y += w.x * xv.y; c0.z += w.x * xv.z; c0.w += w.x * xv.w;
                c1.x += w.y * xv.x; c1.y += w.y * xv.y; c1.z += w.y * xv.z; c1.w += w.y * xv.w;
                c2.x += w.z * xv.x; c2.y += w.z * xv.y; c2.z += w.z * xv.z; c2.w += w.z * xv.w;
                c3.x += w.w * xv.x; c3.y += w.w * xv.y; c3.z += w.w * xv.z; c3.w += w.w * xv.w;
            }
        }
        float4 cc[4] = {c0, c1, c2, c3};
        #pragma unroll
        for (int oo = 0; oo < 4; ++oo) {
            int o = oq * 4 + oo;
            if (o < 62) {
                float bias = cb[o], gg = bng[o] * bninv, bb = bnb[o];
                float v0 = (cc[oo].x + bias) * gg + bb;
                float v1 = (cc[oo].y + bias) * gg + bb;
                float v2 = (cc[oo].z + bias) * gg + bb;
                float v3 = (cc[oo].w + bias) * gg + bb;
                float4 r;
                r.x = SELU_F(v0); r.y = SELU_F(v1); r.z = SELU_F(v2); r.w = SELU_F(v3);
                *(float4*)(sOut + (o * ostride + ooff + l) * 4) = r;
            }
        }
    }
    __syncthreads();
}

__device__ void chan_att_g(int tid, float* sIn, int Ls,
                           const float* __restrict__ w1, const float* __restrict__ w2,
                           float* pool, float* hid)
{
    __syncthreads();
    for (int idx = tid; idx < 496; idx += 256) {
        int which = idx >= 248; int r = idx - which * 248;
        int n = r >> 2, g = r & 3;
        float a = 0.f, m = -3.4e38f;
        for (int l = 0; l < Ls; ++l) { float v = sIn[(n * Ls + l) * 4 + g]; a += v; m = fmaxf(m, v); }
        pool[(which * 62 + n) * 4 + g] = which ? m : a / (float)Ls;
    }
    __syncthreads();
    if (tid < 120) {
        int g = tid & 3; int t = tid >> 2;
        int which = t / 15, j = t - which * 15;
        float acc = 0.f;
        for (int n = 0; n < 62; ++n) acc += pool[(which * 62 + n) * 4 + g] * w1[j * 62 + n];
        hid[(which * 16 + j) * 4 + g] = fmaxf(acc, 0.f);
    }
    __syncthreads();
    if (tid < 248) {
        int g = tid & 3, n = tid >> 2;
        float acc = 0.f;
        for (int j = 0; j < 15; ++j) acc += (hid[j * 4 + g] + hid[(16 + j) * 4 + g]) * w2[n * 15 + j];
        float s = 1.f / (1.f + expf(-acc));
        for (int l = 0; l < Ls; ++l) sIn[(n * Ls + l) * 4 + g] *= s;
    }
    __syncthreads();
}

// ================= FUSED conv + qkv =================
// R17: k_conv (512 blocks) and k_qkv (896 blocks) are data-independent (both read
// g_xin; write g_xx1 / g_qkv; first join at k_gat). One grid: blocks [0,convblks)
// run conv (VALU/L1-bound), the rest run qkv (LDS-broadcast-bound) — complementary
// pipes co-resident per CU. LDS = union (conv layout, 51.6KB).
__global__ __launch_bounds__(256) void k_convqkv(int convblks)
{
    __shared__ __align__(16) float smem[12896];   // conv: sx2|sbuf|sxx1 ; qkv: sxf[4960]
    const int tid = threadIdx.x;

    if ((int)blockIdx.x < convblks) {
        // ---------------- conv path (R16 k_conv body) ----------------
        const int grp = blockIdx.x;
        float* sx2  = smem;            // [1984]
        float* sbuf = smem + 1984;     // [3472]
        float* sxx1 = smem + 5456;     // [7440]
        const float* cw3T = g_cwT;
        const float* cw5T = g_cwT + CW3T_SZ;
        float* spool = sbuf;           // sbuf dead during both chan_att calls
        float* shid  = sbuf + 496;

        for (int idx = tid; idx < 310 * 4; idx += 256) {
            int p = idx >> 2, g = idx & 3; int n = p / 5, c = p - n * 5;
            sx2[(n * 8 + 3 + c) * 4 + g] = g_xin[(size_t)(grp * 4 + g) * 310 + p];
        }
        __syncthreads();

        conv_g<3>(tid, sx2 + 12, 8, 3, cw3T, g_cb3, g_bng, g_bnb, sx2, 8, 0);
        chan_att_g(tid, sx2, 8, g_caw1, g_caw2, spool, shid);

        conv_g<3>(tid, sx2, 8, 6, cw3T + CW3T_ONE, g_cb3 + 62, g_bng + 62, g_bnb + 62, sbuf, 14, 8);
        for (int idx = tid; idx < 496 * 4; idx += 256) {
            int p = idx >> 2, g = idx & 3; int n = p >> 3, c = p & 7;
            sbuf[(n * 14 + c) * 4 + g] = sx2[idx];
        }
        __syncthreads();
        conv_g<3>(tid, sbuf, 14, 12, cw3T + 2 * CW3T_ONE, g_cb3 + 124, g_bng + 124, g_bnb + 124, sxx1, 30, 0);

        conv_g<5>(tid, sx2, 8, 4, cw5T, g_cb5, g_bng + 186, g_bnb + 186, sbuf, 12, 0);
        for (int idx = tid; idx < 496 * 4; idx += 256) {
            int p = idx >> 2, g = idx & 3; int n = p >> 3, c = p & 7;
            sbuf[(n * 12 + 4 + c) * 4 + g] = sx2[idx];
        }
        __syncthreads();
        conv_g<5>(tid, sbuf, 12, 8, cw5T + CW5T_ONE, g_cb5 + 62, g_bng + 248, g_bnb + 248, sxx1, 30, 12);

        conv_g<3>(tid, sx2, 8, 6, cw3T + 3 * CW3T_ONE, g_cb3 + 186, g_bng + 310, g_bnb + 310, sbuf, 14, 0);
        for (int idx = tid; idx < 496 * 4; idx += 256) {
            int p = idx >> 2, g = idx & 3; int n = p >> 3, c = p & 7;
            sbuf[(n * 14 + 6 + c) * 4 + g] = sx2[idx];
        }
        __syncthreads();
        conv_g<5>(tid, sbuf, 14, 10, cw5T + 2 * CW5T_ONE, g_cb5 + 124, g_bng + 372, g_bnb + 372, sxx1, 30, 20);

        chan_att_g(tid, sxx1, 30, g_caw1 + 930, g_caw2 + 930, spool, shid);

        for (int idx = tid; idx < 1860 * 4; idx += 256) {
            int p = idx >> 2, g = idx & 3;
            g_xx1[(size_t)(grp * 4 + g) * 1860 + p] = sxx1[idx];
        }
        return;
    }

    // ---------------- qkv path (R16 k_qkv body) ----------------
    {
        const int bid = blockIdx.x - convblks;
        const int grp = bid / 7;
        const int tile = bid - grp * 7;
        float* sxf = smem;             // [310*16 = 4960]

        for (int idx = tid; idx < 310 * 16; idx += 256) {
            int f = idx >> 4, g = idx & 15;
            sxf[idx] = g_xin[(size_t)(grp * 16 + g) * 310 + f];
        }
        __syncthreads();
        // LN1 in place
        for (int it = tid; it < 992; it += 256) {
            int i = it >> 4, g = it & 15;
            float xv[5], m = 0.f, s = 0.f;
            #pragma unroll
            for (int c = 0; c < 5; ++c) { xv[c] = sxf[(i * 5 + c) * 16 + g]; m += xv[c]; s += xv[c] * xv[c]; }
            m *= 0.2f;
            float inv = rsqrtf(fmaxf(s * 0.2f - m * m, 0.f) + 1e-5f);
            #pragma unroll
            for (int c = 0; c < 5; ++c)
                sxf[(i * 5 + c) * 16 + g] = (xv[c] - m) * inv * g_ln1g[c] + g_ln1bb[c];
        }
        __syncthreads();

        int o0 = tile * 512 + tid;
        if (o0 >= 3348) return;
        int o1 = o0 + 256;
        const int valid1 = (o1 < 3348);
        int o1c = valid1 ? o1 : 3347;

        float bias0 = (o0 < 744) ? g_qb[o0] : (o0 < 1488) ? g_kb[o0 - 744] : g_vb[o0 - 1488];
        float bias1 = (o1c < 744) ? g_qb[o1c] : (o1c < 1488) ? g_kb[o1c - 744] : g_vb[o1c - 1488];
        const float* W0 = g_qkvT + (size_t)o0 * 312;
        const float* W1 = g_qkvT + (size_t)o1c * 312;

        float accA[16], accB[16];
        #pragma unroll
        for (int g = 0; g < 16; ++g) { accA[g] = bias0; accB[g] = bias1; }

#define QS2(wka, wkb, ff) { \
    const float4* xp = (const float4*)(sxf + (ff) * 16); \
    const float4 x0 = xp[0], x1 = xp[1], x2 = xp[2], x3 = xp[3]; \
    float xs[16]; \
    *(float4*)(xs) = x0; *(float4*)(xs + 4) = x1; *(float4*)(xs + 8) = x2; *(float4*)(xs + 12) = x3; \
    _Pragma("unroll") \
    for (int g = 0; g < 16; ++g) { accA[g] += (wka) * xs[g]; accB[g] += (wkb) * xs[g]; } }

        for (int f = 0; f < 308; f += 4) {
            const float4 wa = *(const float4*)(W0 + f);
            const float4 wb = *(const float4*)(W1 + f);
            QS2(wa.x, wb.x, f) QS2(wa.y, wb.y, f + 1) QS2(wa.z, wb.z, f + 2) QS2(wa.w, wb.w, f + 3)
        }
        QS2(W0[308], W1[308], 308) QS2(W0[309], W1[309], 309)
#undef QS2

        #pragma unroll
        for (int g = 0; g < 16; ++g) {
            size_t base = (size_t)(grp * 16 + g) * 3348;
            g_qkv[base + o0] = accA[g];
            if (valid1) g_qkv[base + o1] = accB[g];
        }
    }
}

// per-sample attention -> g_x2t (R16-proven: fused QK^T+max, rcp-fused v-fold)
__global__ __launch_bounds__(256) void k_attn()
{
    __shared__ float sqkv[3348];
    __shared__ float satt[3844];
    __shared__ float sred[496];
    const int tid = threadIdx.x;
    const int b = blockIdx.x;

    for (int i = tid; i < 3348; i += 256) sqkv[i] = g_qkv[(size_t)b * 3348 + i];
    __syncthreads();

    for (int h = 0; h < 6; ++h) {
        const float* q = sqkv + h * 124;
        const float* k = sqkv + 744 + h * 124;
        float* v = sqkv + 1488 + h * 310;
        if (tid < 248) {
            int qq = tid / 62, i = tid - qq * 62;
            int j0 = qq * 16, j1 = j0 + 16 > 62 ? 62 : j0 + 16;
            float qa = q[i * 2], qb2 = q[i * 2 + 1];
            float* row = satt + i * 62;
            float mx = -3.4e38f;
            for (int j = j0; j < j1; ++j) {
                float s = (qa * k[j * 2] + qb2 * k[j * 2 + 1]) * INV_SQRT2;
                row[j] = s;
                mx = fmaxf(mx, s);
            }
            sred[qq * 62 + i] = mx;
        }
        __syncthreads();
        if (tid < 248) {
            int qq = tid / 62, i = tid - qq * 62;
            int j0 = qq * 16, j1 = j0 + 16 > 62 ? 62 : j0 + 16;
            float rmx = fmaxf(fmaxf(sred[i], sred[62 + i]), fmaxf(sred[124 + i], sred[186 + i]));
            float* row = satt + i * 62;
            float s = 0.f;
            for (int j = j0; j < j1; ++j) { float e = expf(row[j] - rmx); row[j] = e; s += e; }
            sred[248 + qq * 62 + i] = s;
        }
        __syncthreads();
        for (int t = tid; t < 310; t += 256) {
            int j = t / 5;
            float inv = 1.f / (sred[248 + j] + sred[310 + j] + sred[372 + j] + sred[434 + j]);
            v[t] *= inv;
        }
        __syncthreads();
        for (int idx = tid; idx < 310; idx += 256) {
            int i = idx / 5, c = idx - i * 5;
            float acc = 0.f;
            for (int j = 0; j < 62; ++j) acc += satt[j * 62 + i] * v[j * 5 + c];
            g_x2t[(size_t)b * 1860 + i * 30 + h * 5 + c] = acc;
        }
        __syncthreads();
    }
}

// lin1 + residual + LN2 + FFN + residual (R16-proven: lin1 thirds)
__global__ __launch_bounds__(256) void k_lin1ffn()
{
    __shared__ __align__(16) float sx2t[1860 * 4];
    __shared__ __align__(16) float sX[310 * 4];
    __shared__ __align__(16) float sx21[310 * 4];
    __shared__ __align__(16) float sxf[310 * 4];
    __shared__ __align__(16) float shg[186 * 4];
    __shared__ __align__(16) float spart[930 * 4];
    const int tid = threadIdx.x;
    const int grp = blockIdx.x;

    for (int idx = tid; idx < 1860 * 4; idx += 256) {
        int f = idx >> 2, g = idx & 3;
        sx2t[idx] = g_x2t[(size_t)(grp * 4 + g) * 1860 + f];
    }
    for (int idx = tid; idx < 310 * 4; idx += 256) {
        int o = idx >> 2, g = idx & 3;
        sX[idx] = g_xin[(size_t)(grp * 4 + g) * 310 + o];
    }
    __syncthreads();

#define XSTEP(wk, ff, Xb) { const float4 xv = *(const float4*)((Xb) + (ff) * 4); \
                            a0 += (wk) * xv.x; a1 += (wk) * xv.y; a2 += (wk) * xv.z; a3 += (wk) * xv.w; }
    for (int item = tid; item < 930; item += 256) {
        int t = item / 310, o = item - t * 310;
        const float* W = g_lin1T + (size_t)o * 1860 + t * 620;
        const float* Xb = sx2t + t * 620 * 4;
        float a0 = 0.f, a1 = 0.f, a2 = 0.f, a3 = 0.f;
        for (int f = 0; f < 620; f += 4) {
            const float4 w = *(const float4*)(W + f);
            XSTEP(w.x, f, Xb) XSTEP(w.y, f + 1, Xb) XSTEP(w.z, f + 2, Xb) XSTEP(w.w, f + 3, Xb)
        }
        spart[item * 4 + 0] = a0; spart[item * 4 + 1] = a1;
        spart[item * 4 + 2] = a2; spart[item * 4 + 3] = a3;
    }
    __syncthreads();
    for (int o = tid; o < 310; o += 256) {
        float bias = g_lin1b[o];
        for (int g = 0; g < 4; ++g)
            sx21[o * 4 + g] = spart[o * 4 + g] + spart[(310 + o) * 4 + g] + spart[(620 + o) * 4 + g]
                            + bias + sX[o * 4 + g];
    }
    __syncthreads();

    if (tid < 248) {
        int i = tid >> 2, g = tid & 3;
        float m = 0.f, s = 0.f;
        for (int c = 0; c < 5; ++c) { float v = sx21[(i * 5 + c) * 4 + g]; m += v; s += v * v; }
        m *= 0.2f;
        float inv = rsqrtf(fmaxf(s * 0.2f - m * m, 0.f) + 1e-5f);
        for (int c = 0; c < 5; ++c)
            sxf[(i * 5 + c) * 4 + g] = (sx21[(i * 5 + c) * 4 + g] - m) * inv * g_ln2g[c] + g_ln2bb[c];
    }
    __syncthreads();

    if (tid < 186) {
        const float* W = g_ffn1T + (size_t)tid * 312;
        float bias = g_ffnb1[tid];
        float a0 = bias, a1 = bias, a2 = bias, a3 = bias;
        for (int f = 0; f < 308; f += 4) {
            const float4 w = *(const float4*)(W + f);
            XSTEP(w.x, f, sxf) XSTEP(w.y, f + 1, sxf) XSTEP(w.z, f + 2, sxf) XSTEP(w.w, f + 3, sxf)
        }
        XSTEP(W[308], 308, sxf) XSTEP(W[309], 309, sxf)
        shg[tid * 4 + 0] = 0.5f * a0 * (1.f + erff(a0 * INV_SQRT2));
        shg[tid * 4 + 1] = 0.5f * a1 * (1.f + erff(a1 * INV_SQRT2));
        shg[tid * 4 + 2] = 0.5f * a2 * (1.f + erff(a2 * INV_SQRT2));
        shg[tid * 4 + 3] = 0.5f * a3 * (1.f + erff(a3 * INV_SQRT2));
    }
    __syncthreads();

    for (int o = tid; o < 310; o += 256) {
        const float* W = g_ffn2T + (size_t)o * 188;
        float bias = g_ffnb2[o];
        float a0 = bias, a1 = bias, a2 = bias, a3 = bias;
        for (int j = 0; j < 184; j += 4) {
            const float4 w = *(const float4*)(W + j);
            XSTEP(w.x, j, shg) XSTEP(w.y, j + 1, shg) XSTEP(w.z, j + 2, shg) XSTEP(w.w, j + 3, shg)
        }
        XSTEP(W[184], 184, shg) XSTEP(W[185], 185, shg)
        g_xt[(size_t)(grp * 4 + 0) * 310 + o] = a0 + sx21[o * 4 + 0];
        g_xt[(size_t)(grp * 4 + 1) * 310 + o] = a1 + sx21[o * 4 + 1];
        g_xt[(size_t)(grp * 4 + 2) * 310 + o] = a2 + sx21[o * 4 + 2];
        g_xt[(size_t)(grp * 4 + 3) * 310 + o] = a3 + sx21[o * 4 + 3];
    }
#undef XSTEP
}

// ================= GAT (R9-proven: fold passes + register layer-2 accum) =================
__global__ __launch_bounds__(256) void k_gat(void* __restrict__ out, int B)
{
    __shared__ __align__(16) float satt[3844];
    __shared__ __align__(16) float sh[1984];
    __shared__ __align__(16) float sbufA[2170];   // layer1: f32 sxx; layer2: soutg
    __shared__ float ssrc[124];
    __shared__ float sred[496];
    __shared__ float sacc2[620];
    const int tid = threadIdx.x;
    const int b = blockIdx.x;
    const int isbf = g_flag;
    float* sxx = sbufA;

    for (int idx = tid; idx < 2170; idx += 256) {
        int n = idx / 35, f = idx - n * 35;
        sxx[idx] = (f < 30) ? g_xx1[(size_t)b * 1860 + n * 30 + f]
                            : g_xt[(size_t)b * 310 + n * 5 + (f - 30)];
    }

    float racc0[10], racc1[10];
    #pragma unroll
    for (int o = 0; o < 10; ++o) { racc0[o] = 0.f; racc1[o] = 0.f; }

    for (int h = 0; h < 4; ++h) {
        for (int idx = tid; idx < 1120; idx += 256) satt[idx] = g_gatW[h * 1120 + idx];
        __syncthreads();
        float* sp1 = satt + 1200;
        float* sp2 = satt + 1800;
        for (int item = tid; item < 496; item += 256) {
            int n = item >> 3, oqi = item & 7, oq = oqi * 4;
            const float* xr = sxx + n * 35;
            float a0 = 0.f, a1 = 0.f, a2 = 0.f, a3 = 0.f;
            for (int f = 0; f < 35; ++f) {
                float xv = xr[f];
                const float4 w = *(const float4*)(satt + f * 32 + oq);
                a0 += xv * w.x; a1 += xv * w.y; a2 += xv * w.z; a3 += xv * w.w;
            }
            float4 r; r.x = a0; r.y = a1; r.z = a2; r.w = a3;
            *(float4*)(sh + n * 32 + oq) = r;
            float l0 = a0 > 0.f ? a0 : 0.2f * a0;
            float l1 = a1 > 0.f ? a1 : 0.2f * a1;
            float l2 = a2 > 0.f ? a2 : 0.2f * a2;
            float l3 = a3 > 0.f ? a3 : 0.2f * a3;
            const float* ga = g_gata + h * 64 + oq;
            sp1[n * 9 + oqi] = l0 * ga[0] + l1 * ga[1] + l2 * ga[2] + l3 * ga[3];
            sp2[n * 9 + oqi] = l0 * ga[32] + l1 * ga[33] + l2 * ga[34] + l3 * ga[35];
        }
        __syncthreads();
        if (tid < 124) {
            int which = tid >= 62; int n = tid - which * 62;
            const float* pp = which ? sp2 : sp1;
            float s = 0.f;
            for (int q = 0; q < 8; ++q) s += pp[n * 9 + q];
            ssrc[tid] = s;
        }
        __syncthreads();
        if (tid < 248) {
            int q = tid / 62, m = tid - q * 62;
            int n0 = q * 16, n1 = n0 + 16 > 62 ? 62 : n0 + 16;
            float s2m = ssrc[62 + m];
            float mx = -3.4e38f;
            for (int n = n0; n < n1; ++n) {
                float dj = 0.8f * g_L[n * 62 + m] + 0.2f * (ssrc[n] + s2m);
                dj = dj > 0.f ? dj : -1e12f;
                satt[n * 62 + m] = dj;
                mx = fmaxf(mx, dj);
            }
            sred[q * 62 + m] = mx;
        }
        __syncthreads();
        if (tid < 248) {
            int q = tid / 62, m = tid - q * 62;
            int n0 = q * 16, n1 = n0 + 16 > 62 ? 62 : n0 + 16;
            float cmx = fmaxf(fmaxf(sred[m], sred[62 + m]), fmaxf(sred[124 + m], sred[186 + m]));
            float s = 0.f;
            for (int n = n0; n < n1; ++n) {
                float e = expf(satt[n * 62 + m] - cmx);
                satt[n * 62 + m] = e;
                s += e;
            }
            sred[248 + q * 62 + m] = s;
        }
        __syncthreads();
        if (tid < 62)
            ssrc[tid] = 1.f / (sred[248 + tid] + sred[310 + tid] + sred[372 + tid] + sred[434 + tid]);
        __syncthreads();
        for (int item = tid; item < 1984; item += 256) sh[item] *= ssrc[item >> 5];
        __syncthreads();
        if (tid < 248) {
            int ip = tid >> 3, oqi = tid & 7, oq = oqi * 4;
            int i0 = ip * 2;
            const float* ar0 = satt + i0 * 62;
            const float* ar1 = ar0 + 62;
            float a00 = 0.f, a01 = 0.f, a02 = 0.f, a03 = 0.f;
            float a10 = 0.f, a11 = 0.f, a12 = 0.f, a13 = 0.f;
            for (int j = 0; j < 62; ++j) {
                const float4 hv = *(const float4*)(sh + j * 32 + oq);
                float v0 = ar0[j], v1 = ar1[j];
                a00 += v0 * hv.x; a01 += v0 * hv.y; a02 += v0 * hv.z; a03 += v0 * hv.w;
                a10 += v1 * hv.x; a11 += v1 * hv.y; a12 += v1 * hv.z; a13 += v1 * hv.w;
            }
            a00 = fmaxf(a00, 0.f); a01 = fmaxf(a01, 0.f); a02 = fmaxf(a02, 0.f); a03 = fmaxf(a03, 0.f);
            a10 = fmaxf(a10, 0.f); a11 = fmaxf(a11, 0.f); a12 = fmaxf(a12, 0.f); a13 = fmaxf(a13, 0.f);
            const float* W2 = g_outW + (h * 32 + oq) * 10;
            #pragma unroll
            for (int o = 0; o < 10; ++o) {
                float w0 = W2[o], w1 = W2[10 + o], w2c = W2[20 + o], w3 = W2[30 + o];
                racc0[o] += a00 * w0 + a01 * w1 + a02 * w2c + a03 * w3;
                racc1[o] += a10 * w0 + a11 * w1 + a12 * w2c + a13 * w3;
            }
        }
        __syncthreads();
    }

    if (tid < 248) {
        float* dst = satt + tid * 20;
        #pragma unroll
        for (int o = 0; o < 10; ++o) { dst[o] = racc0[o]; dst[10 + o] = racc1[o]; }
    }
    __syncthreads();
    for (int idx = tid; idx < 620; idx += 256) {
        int i = idx / 10, o = idx - i * 10;
        int ip = i >> 1, half = i & 1;
        const float* src = satt + (ip * 8) * 20 + half * 10 + o;
        float s = 0.f;
        #pragma unroll
        for (int q = 0; q < 8; ++q) s += src[q * 20];
        sacc2[idx] = s;
    }
    __syncthreads();

    float* sh2   = sacc2;
    float* soutg = sbufA;

    if (tid < 124) {
        int which = tid >= 62; int n = tid - which * 62;
        float acc = 0.f;
        for (int o = 0; o < 10; ++o) {
            float v = sh2[n * 10 + o]; v = v > 0.f ? v : 0.2f * v;
            acc += v * g_outa[which * 10 + o];
        }
        ssrc[tid] = acc;
    }
    __syncthreads();
    if (tid < 248) {
        int q = tid / 62, m = tid - q * 62;
        int n0 = q * 16, n1 = n0 + 16 > 62 ? 62 : n0 + 16;
        float s2m = ssrc[62 + m];
        float mx = -3.4e38f;
        for (int n = n0; n < n1; ++n) {
            float dj = 0.8f * g_L[n * 62 + m] + 0.2f * (ssrc[n] + s2m);
            dj = dj > 0.f ? dj : -1e12f;
            satt[n * 62 + m] = dj;
            mx = fmaxf(mx, dj);
        }
        sred[q * 62 + m] = mx;
    }
    __syncthreads();
    if (tid < 248) {
        int q = tid / 62, m = tid - q * 62;
        int n0 = q * 16, n1 = n0 + 16 > 62 ? 62 : n0 + 16;
        float cmx = fmaxf(fmaxf(sred[m], sred[62 + m]), fmaxf(sred[124 + m], sred[186 + m]));
        float s = 0.f;
        for (int n = n0; n < n1; ++n) {
            float e = expf(satt[n * 62 + m] - cmx);
            satt[n * 62 + m] = e;
            s += e;
        }
        sred[248 + q * 62 + m] = s;
    }
    __syncthreads();
    if (tid < 62)
        ssrc[tid] = 1.f / (sred[248 + tid] + sred[310 + tid] + sred[372 + tid] + sred[434 + tid]);
    __syncthreads();
    for (int item = tid; item < 620; item += 256) sh2[item] *= ssrc[item / 10];
    __syncthreads();
    for (int idx = tid; idx < 620; idx += 256) {
        int i = idx / 10, o = idx - i * 10;
        const float* ar = satt + i * 62;
        float acc = 0.f;
        for (int j = 0; j < 62; ++j) acc += ar[j] * sh2[j * 10 + o];
        soutg[idx] = fmaxf(acc, 0.f);
    }
    __syncthreads();

    if (tid < 62) {
        const float* r = soutg + tid * 10;
        float e[10]; float mx = -3.4e38f;
        for (int o = 0; o < 10; ++o) { float v = r[o]; v = v > 0.f ? v : expm1f(v); e[o] = v; mx = fmaxf(mx, v); }
        float sum = 0.f;
        for (int o = 0; o < 10; ++o) sum += expf(e[o] - mx);
        float ls = logf(sum) + mx;
        for (int o = 0; o < 10; ++o) {
            float v = e[o] - ls;
            size_t off = (size_t)b * 620 + tid * 10 + o;
            if (isbf) ((bf16*)out)[off] = f2b(v); else ((float*)out)[off] = v;
            g_x11f[off] = v;
        }
    }
}

// fc1->fc2->fc3 tail, 8 samples/block (R6-proven)
__global__ __launch_bounds__(256) void k_fc(void* __restrict__ out, int B)
{
    __shared__ __align__(16) float sxf[620 * 8];
    __shared__ __align__(16) float st1[256 * 8];
    __shared__ __align__(16) float st2[32 * 8];
    const int tid = threadIdx.x;
    const int grp = blockIdx.x;
    const int isbf = g_flag;

    for (int idx = tid; idx < 620 * 8; idx += 256) {
        int f = idx >> 3, g = idx & 7;
        sxf[idx] = g_x11f[(size_t)(grp * 8 + g) * 620 + f];
    }
    __syncthreads();

    {
        const float* W = g_fc1T + (size_t)tid * 620;
        float bias = g_fc1b[tid];
        float a0 = bias, a1 = bias, a2 = bias, a3 = bias, a4 = bias, a5 = bias, a6 = bias, a7 = bias;
#define FSTEP(wk, ff) { const float4 p = *(const float4*)(sxf + (ff) * 8); \
                        const float4 qq = *(const float4*)(sxf + (ff) * 8 + 4); \
                        a0 += (wk) * p.x; a1 += (wk) * p.y; a2 += (wk) * p.z; a3 += (wk) * p.w; \
                        a4 += (wk) * qq.x; a5 += (wk) * qq.y; a6 += (wk) * qq.z; a7 += (wk) * qq.w; }
        for (int f = 0; f < 620; f += 4) {
            const float4 w = *(const float4*)(W + f);
            FSTEP(w.x, f) FSTEP(w.y, f + 1) FSTEP(w.z, f + 2) FSTEP(w.w, f + 3)
        }
#undef FSTEP
        float4 r0; r0.x = a0; r0.y = a1; r0.z = a2; r0.w = a3;
        float4 r1; r1.x = a4; r1.y = a5; r1.z = a6; r1.w = a7;
        *(float4*)(st1 + tid * 8)     = r0;
        *(float4*)(st1 + tid * 8 + 4) = r1;
    }
    __syncthreads();
    {
        int g = tid >> 5, o = tid & 31;
        float acc = g_fc2b[o];
        for (int f = 0; f < 256; ++f) acc += st1[f * 8 + g] * g_fc2w[f * 32 + o];
        st2[o * 8 + g] = acc;
    }
    __syncthreads();
    if (tid < 32) {
        int g = tid >> 2, o = tid & 3;
        float acc = g_fc3b[o];
        for (int f = 0; f < 32; ++f) acc += st2[f * 8 + g] * g_fc3w[f * 4 + o];
        size_t off = (size_t)B * 620 + (size_t)(grp * 8 + g) * 4 + o;
        if (isbf) ((bf16*)out)[off] = f2b(acc); else ((float*)out)[off] = acc;
    }
}

extern "C" void kernel_launch(void* const* d_in, const int* in_sizes, int n_in,
                              void* d_out, int out_size, void* d_ws, size_t ws_size,
                              hipStream_t stream)
{
    const int B = in_sizes[0] / 310;   // 2048
    const int wprep_blocks = (WPREP_TOTAL + 255) / 256;
    const int convblks = B / 4;        // 512
    const int qkvblks  = (B / 16) * 7; // 896

    k_probe<<<1, 256, 0, stream>>>(d_in[0]);

    k_wprep<<<wprep_blocks, 256, 0, stream>>>(
        d_in[10], d_in[12], d_in[14], d_in[16], d_in[22], d_in[24], d_in[30],
        d_in[26], d_in[28], d_in[0], d_in[2], d_in[4]);
    k_prep<<<72, 256, 0, stream>>>(
        d_in[1], d_in[3], d_in[5], d_in[6], d_in[7], d_in[8], d_in[9],
        d_in[11], d_in[13], d_in[15], d_in[17], d_in[18], d_in[19], d_in[20], d_in[21],
        d_in[23], d_in[25], d_in[27], d_in[29],
        d_in[31], d_in[32], d_in[33], d_in[34], d_in[35]);

    k_convqkv<<<convblks + qkvblks, 256, 0, stream>>>(convblks);
    k_attn<<<B, 256, 0, stream>>>();
    k_lin1ffn<<<B / 4, 256, 0, stream>>>();
    k_gat<<<B, 256, 0, stream>>>(d_out, B);
    k_fc<<<B / 8, 256, 0, stream>>>(d_out, B);
}